// Round 8
// baseline (260.251 us; speedup 1.0000x reference)
//
#include <hip/hip_runtime.h>

// ---------- common ----------
typedef short sh8 __attribute__((ext_vector_type(8)));
typedef float f32x4 __attribute__((ext_vector_type(4)));

#define DEV __device__ __forceinline__

DEV f32x4 mfma16(sh8 a, sh8 b, f32x4 c) {
  return __builtin_amdgcn_mfma_f32_16x16x32_bf16(a, b, c, 0, 0, 0);
}

DEV unsigned short f2bf(float f) {
  unsigned u = __float_as_uint(f);
  u = u + 0x7FFFu + ((u >> 16) & 1u);   // RNE
  return (unsigned short)(u >> 16);
}

DEV unsigned cvtpk(float lo, float hi) {
  unsigned r;
  asm("v_cvt_pk_bf16_f32 %0, %1, %2" : "=v"(r) : "v"(lo), "v"(hi));
  return r;
}

DEV void gll16(const void* g, void* l) {
  __builtin_amdgcn_global_load_lds(
      (const __attribute__((address_space(1))) unsigned int*)g,
      (__attribute__((address_space(3))) unsigned int*)l, 16, 0, 0);
}

// ---------- kernel: x fp32 -> bf16 ----------
__global__ void cvt_x_kernel(const float* __restrict__ x, unsigned short* __restrict__ xb, int n4) {
  int i = blockIdx.x * blockDim.x + threadIdx.x;
  int stride = gridDim.x * blockDim.x;
  for (; i < n4; i += stride) {
    float4 v = ((const float4*)x)[i];
    ushort4 o;
    o.x = f2bf(v.x); o.y = f2bf(v.y); o.z = f2bf(v.z); o.w = f2bf(v.w);
    ((ushort4*)xb)[i] = o;
  }
}

// ---------- kernel: weight transpose + cvt ----------
__global__ void cvt_wT_kernel(const float* __restrict__ W0, const float* __restrict__ W1,
                              const float* __restrict__ W2, const float* __restrict__ W3,
                              unsigned short* __restrict__ T0, unsigned short* __restrict__ T1,
                              unsigned short* __restrict__ T2, unsigned short* __restrict__ T3) {
  const float* W; unsigned short* T;
  switch (blockIdx.z) {
    case 0: W = W0; T = T0; break;
    case 1: W = W1; T = T1; break;
    case 2: W = W2; T = T2; break;
    default: W = W3; T = T3; break;
  }
  __shared__ float tile[32][33];
  int tx = threadIdx.x & 31, ty = threadIdx.x >> 5;
  int r0 = blockIdx.y * 32, c0 = blockIdx.x * 32;
#pragma unroll
  for (int i = 0; i < 4; i++) tile[ty + i * 8][tx] = W[(r0 + ty + i * 8) * 512 + c0 + tx];
  __syncthreads();
#pragma unroll
  for (int i = 0; i < 4; i++) T[(c0 + ty + i * 8) * 512 + r0 + tx] = f2bf(tile[tx][ty + i * 8]);
}

// ================= 256x256 8-phase U-GEMM =================
// U[8192][8192] = exp2(scale * Q[8192][512] @ K^T), + per-row partial sums.
// 8 waves (wm2 = w&1 over M-halves' rows, wn4 = w>>1 over 32-col strips).
// LDS 128KB: buf{0,1} x {A[256][64], B[256][64]}, halves = 128 rows.
// Phase = quadrant (mh,nh) of C over full K=64: 12 ds_read + 1 half-tile
// stage + barrier + 16 MFMA + barrier. vmcnt(4) once per K-tile (at j3).
__global__ __launch_bounds__(512, 2) void gemm256_u_kernel(
    const unsigned short* __restrict__ Q, const unsigned short* __restrict__ Kb,
    unsigned short* __restrict__ U, float* __restrict__ lpart) {
  __shared__ __align__(16) unsigned short smem[65536];
  const int tid = threadIdx.x, lane = tid & 63;
  const int w = tid >> 6;
  const int g = lane >> 4, r = lane & 15;
  const int wm2 = w & 1, wn4 = w >> 1;
  const int wgid = (blockIdx.x & 7) * 128 + (blockIdx.x >> 3);  // XCD swizzle (1024%8==0)
  const int brow = (wgid >> 5) * 256;
  const int bcol = (wgid & 31) * 256;
  const int srow = tid >> 3;      // staging row 0..63
  const int sg = tid & 7;         // staging granule

  f32x4 acc[2][2][4][2] = {};

  // stage half-tile: array a (0=A from Q, 1=B from Kb), half h, buf b, k-tile kt
#define STG(b, a, h, kt)                                                              \
  do {                                                                                \
    const unsigned short* _src = (a) ? Kb : Q;                                        \
    int _base = (a) ? bcol : brow;                                                    \
    int _r0 = (h) * 128 + srow;                                                       \
    int _r1 = _r0 + 64;                                                               \
    unsigned short* _d = smem + (b) * 32768 + (a) * 16384 + (h) * 8192 + tid * 8;     \
    gll16(_src + (size_t)(_base + _r0) * 512 + (kt) * 64 + ((sg ^ (_r0 & 7)) * 8), _d);      \
    gll16(_src + (size_t)(_base + _r1) * 512 + (kt) * 64 + ((sg ^ (_r1 & 7)) * 8), _d + 4096); \
  } while (0)

  // phase: compute quadrant (MH,NH) of buf B_, staging (sb,sa,sh_,skt); DOVM -> vmcnt(4)
#define PH(B_, MH, NH, sb, sa, sh_, skt, DOVM)                                        \
  do {                                                                                \
    const unsigned short* _As = smem + (B_) * 32768;                                  \
    const unsigned short* _Bs = _As + 16384;                                          \
    sh8 _af[2][4], _bf[2][2];                                                         \
    _Pragma("unroll") for (int kk = 0; kk < 2; kk++) {                                \
      _Pragma("unroll") for (int m = 0; m < 4; m++) {                                 \
        int _row = (MH) * 128 + wm2 * 64 + m * 16 + r;                                \
        _af[kk][m] = *(const sh8*)&_As[_row * 64 + (((kk * 4 + g) ^ (r & 7)) * 8)];   \
      }                                                                               \
      _Pragma("unroll") for (int n = 0; n < 2; n++) {                                 \
        int _row = (NH) * 128 + wn4 * 32 + n * 16 + r;                                \
        _bf[kk][n] = *(const sh8*)&_Bs[_row * 64 + (((kk * 4 + g) ^ (r & 7)) * 8)];   \
      }                                                                               \
    }                                                                                 \
    STG(sb, sa, sh_, skt);                                                            \
    if (DOVM) asm volatile("s_waitcnt vmcnt(4)" ::: "memory");                        \
    asm volatile("s_barrier" ::: "memory");                                           \
    __builtin_amdgcn_s_setprio(1);                                                    \
    _Pragma("unroll") for (int kk = 0; kk < 2; kk++)                                  \
      _Pragma("unroll") for (int m = 0; m < 4; m++)                                   \
        _Pragma("unroll") for (int n = 0; n < 2; n++)                                 \
          acc[MH][NH][m][n] = mfma16(_af[kk][m], _bf[kk][n], acc[MH][NH][m][n]);      \
    __builtin_amdgcn_s_setprio(0);                                                    \
    asm volatile("s_barrier" ::: "memory");                                           \
  } while (0)

  // prologue: tile0 all 4 halves + tile1 A0,B0; gate tile0
  STG(0, 0, 0, 0); STG(0, 1, 0, 0); STG(0, 0, 1, 0); STG(0, 1, 1, 0);
  STG(1, 0, 0, 1); STG(1, 1, 0, 1);
  asm volatile("s_waitcnt vmcnt(4)" ::: "memory");
  asm volatile("s_barrier" ::: "memory");

  for (int it = 0; it < 4; it++) {
    const int t0 = 2 * it, t1 = 2 * it + 1;
    const int ka = (t0 + 1 < 8) ? t0 + 1 : 7;   // A1/B1 of tile t0+1
    const int kb2 = (t0 + 2 < 8) ? t0 + 2 : 7;  // A0/B0 of tile t0+2
    PH(0, 0, 0, 1, 0, 1, ka, 0);
    PH(0, 0, 1, 1, 1, 1, ka, 0);
    PH(0, 1, 0, 0, 0, 0, kb2, 0);
    PH(0, 1, 1, 0, 1, 0, kb2, 1);
    const int kc = (t1 + 1 < 8) ? t1 + 1 : 7;
    const int kd = (t1 + 2 < 8) ? t1 + 2 : 7;
    PH(1, 0, 0, 0, 0, 1, kc, 0);
    PH(1, 0, 1, 0, 1, 1, kc, 0);
    PH(1, 1, 0, 1, 0, 0, kd, 0);
    PH(1, 1, 1, 1, 1, 0, kd, 1);
  }
#undef PH
#undef STG

  asm volatile("s_waitcnt vmcnt(0)" ::: "memory");
  __syncthreads();

  // epilogue: exp2, per-row partial sums (64-col per wave -> lpart slot), LDS restage
  const float K2c = 0.04419417382415922f * 1.4426950408889634f;  // 1/sqrt(512)*log2e
#pragma unroll
  for (int mh = 0; mh < 2; mh++)
#pragma unroll
    for (int m = 0; m < 4; m++)
#pragma unroll
      for (int i = 0; i < 4; i++) {
        int row = mh * 128 + wm2 * 64 + m * 16 + 4 * g + i;
        float s = 0.f;
#pragma unroll
        for (int nh = 0; nh < 2; nh++)
#pragma unroll
          for (int n = 0; n < 2; n++) {
            float v = __builtin_amdgcn_exp2f(acc[mh][nh][m][n][i] * K2c);
            s += v;
            int col = nh * 128 + wn4 * 32 + n * 16 + r;
            smem[row * 256 + (col ^ ((row & 7) << 3))] = f2bf(v);
          }
        s += __shfl_xor(s, 1); s += __shfl_xor(s, 2);
        s += __shfl_xor(s, 4); s += __shfl_xor(s, 8);
        if (r == 0)
          lpart[(size_t)((bcol >> 6) + wn4) * 8192 + brow + row] = s;
      }
  __syncthreads();
#pragma unroll
  for (int jj = 0; jj < 16; jj++) {
    int row = jj * 16 + (tid >> 5);
    int g32 = tid & 31;
    uint4 v = *(const uint4*)&smem[row * 256 + ((g32 ^ (row & 7)) * 8)];
    *(uint4*)&U[(size_t)(brow + row) * 8192 + bcol + g32 * 8] = v;
  }
}

// ---------- 128x128 GEMM core (BK=64, dbuf + counted vmcnt) ----------
template <int MODE>
DEV void gemm_core(const unsigned short* __restrict__ A, int lda,
                   const unsigned short* __restrict__ Bt, int ldb,
                   const float* __restrict__ bias, void* __restrict__ Cv, int ldc,
                   int kSteps, int koff, int brow, int bcol,
                   float* __restrict__ lpart, unsigned short* smem) {
  const int tid = threadIdx.x, lane = tid & 63, w = tid >> 6;
  const int g = lane >> 4, r = lane & 15;
  const int wr = w >> 1, wc = w & 1;
  const int rA = w * 8 + (lane >> 3);
  const int sgl = lane & 7;
  const int scol = ((sgl ^ (lane >> 3)) * 8);
  const unsigned short* aP = A + (size_t)(brow + rA) * lda + koff + scol;
  const unsigned short* bP = Bt + (size_t)(bcol + rA) * ldb + koff + scol;
  const int lOff = rA * 64 + sgl * 8;
  f32x4 acc[4][4] = {};
  const int fr = r & 7;

  auto STAGE = [&](int buf, int ks) {
    unsigned short* lA = smem + buf * 16384 + lOff;
    unsigned short* lB = smem + buf * 16384 + 8192 + lOff;
    const size_t ko = (size_t)ks * 64;
#pragma unroll
    for (int cc = 0; cc < 4; cc++) gll16(aP + (size_t)cc * 32 * lda + ko, lA + cc * 32 * 64);
#pragma unroll
    for (int cc = 0; cc < 4; cc++) gll16(bP + (size_t)cc * 32 * ldb + ko, lB + cc * 32 * 64);
  };
  auto COMPUTE = [&](int buf) {
    const unsigned short* As = smem + buf * 16384;
    const unsigned short* Bs = As + 8192;
#pragma unroll
    for (int kk = 0; kk < 2; kk++) {
      sh8 af[4], bfr[4];
#pragma unroll
      for (int m = 0; m < 4; m++)
        af[m] = *(const sh8*)&As[(wr * 64 + m * 16 + r) * 64 + (((kk * 4 + g) ^ fr) * 8)];
#pragma unroll
      for (int n = 0; n < 4; n++)
        bfr[n] = *(const sh8*)&Bs[(wc * 64 + n * 16 + r) * 64 + (((kk * 4 + g) ^ fr) * 8)];
#pragma unroll
      for (int m = 0; m < 4; m++)
#pragma unroll
        for (int n = 0; n < 4; n++) acc[m][n] = mfma16(af[m], bfr[n], acc[m][n]);
    }
  };

  STAGE(0, 0);
  int cur = 0;
  for (int ks = 0; ks + 1 < kSteps; ks++) {
    STAGE(cur ^ 1, ks + 1);
    asm volatile("s_waitcnt vmcnt(8)" ::: "memory");
    asm volatile("s_barrier" ::: "memory");
    COMPUTE(cur);
    asm volatile("s_barrier" ::: "memory");
    cur ^= 1;
  }
  asm volatile("s_waitcnt vmcnt(0)" ::: "memory");
  asm volatile("s_barrier" ::: "memory");
  COMPUTE(cur);

  if (MODE == 0) {
#pragma unroll
    for (int n = 0; n < 4; n++) {
      int col = bcol + wc * 64 + n * 16 + r;
      float bv = bias ? bias[col] : 0.f;
#pragma unroll
      for (int m = 0; m < 4; m++) {
        int row = brow + wr * 64 + m * 16 + g * 4;
#pragma unroll
        for (int i = 0; i < 4; i++)
          ((float*)Cv)[(size_t)(row + i) * ldc + col] = acc[m][n][i] + bv;
      }
    }
  } else {
    __syncthreads();
#pragma unroll
    for (int m = 0; m < 4; m++) {
#pragma unroll
      for (int n = 0; n < 4; n++) {
        int coll = wc * 64 + n * 16 + r;
        float bv = bias ? bias[bcol + coll] : 0.f;
        int rb = (wr * 64 + m * 16 + g * 4) * 132 + coll;
        smem[rb] = f2bf(acc[m][n][0] + bv);
        smem[rb + 132] = f2bf(acc[m][n][1] + bv);
        smem[rb + 264] = f2bf(acc[m][n][2] + bv);
        smem[rb + 396] = f2bf(acc[m][n][3] + bv);
      }
    }
    __syncthreads();
    unsigned short* C = (unsigned short*)Cv;
#pragma unroll
    for (int j = 0; j < 8; j++) {
      int row = w * 32 + j * 4 + (lane >> 4);
      int colb = (lane & 15) * 8;
      uint4 v = *(const uint4*)&smem[row * 132 + colb];
      *(uint4*)&C[(size_t)(brow + row) * ldc + bcol + colb] = v;
    }
  }
}

// ---------- GEMM wrappers ----------
__global__ __launch_bounds__(256, 2) void gemm_qkv_kernel(
    const unsigned short* __restrict__ A,
    const unsigned short* __restrict__ B0, const unsigned short* __restrict__ B1,
    const unsigned short* __restrict__ B2,
    const float* __restrict__ c0, const float* __restrict__ c1, const float* __restrict__ c2,
    unsigned short* __restrict__ C0, unsigned short* __restrict__ C1,
    unsigned short* __restrict__ C2) {
  __shared__ __align__(16) unsigned short smem[32768];
  const unsigned short* Bt; const float* bias; unsigned short* C;
  switch (blockIdx.z) {
    case 0: Bt = B0; bias = c0; C = C0; break;
    case 1: Bt = B1; bias = c1; C = C1; break;
    default: Bt = B2; bias = c2; C = C2; break;
  }
  gemm_core<1>(A, 512, Bt, 512, bias, C, 512, 8, 0,
               blockIdx.x * 128, blockIdx.y * 128, nullptr, smem);
}

// PV: 1-D grid of 512; c=bid&7 pins (x-tile, k-split) to an XCD for VT L2 reuse.
__global__ __launch_bounds__(256, 2) void gemm_pv_kernel(
    const unsigned short* __restrict__ U, const unsigned short* __restrict__ VT,
    float* __restrict__ P0, float* __restrict__ P1) {
  __shared__ __align__(16) unsigned short smem[32768];
  const int b = blockIdx.x;
  const int c = b & 7, xt = c & 3, zt = c >> 2, yt = b >> 3;
  float* P = zt ? P1 : P0;
  gemm_core<0>(U, 8192, VT, 8192, nullptr, P, 512, 64, zt * 4096,
               yt * 128, xt * 128, nullptr, smem);
}

__global__ __launch_bounds__(256, 2) void gemm_o_kernel(
    const unsigned short* __restrict__ att, const unsigned short* __restrict__ woT,
    const float* __restrict__ bo, float* __restrict__ out) {
  __shared__ __align__(16) unsigned short smem[32768];
  gemm_core<0>(att, 512, woT, 512, bo, out, 512, 8, 0,
               blockIdx.x * 128, blockIdx.y * 128, nullptr, smem);
}

// ---------- kernel: v [8192][512] -> vT [512][8192] (bf16) ----------
__global__ void transpose_v_kernel(const unsigned short* __restrict__ in, unsigned short* __restrict__ out) {
  __shared__ unsigned short tile[32][33];
  int tx = threadIdx.x & 31, ty = threadIdx.x >> 5;
  int r0 = blockIdx.y * 32, c0 = blockIdx.x * 32;
#pragma unroll
  for (int i = 0; i < 4; i++) tile[ty + i * 8][tx] = in[(size_t)(r0 + ty + i * 8) * 512 + c0 + tx];
  __syncthreads();
#pragma unroll
  for (int i = 0; i < 4; i++) out[(size_t)(c0 + ty + i * 8) * 8192 + r0 + tx] = tile[tx][ty + i * 8];
}

// ---------- combine row-sum partials -> 1/l ----------
__global__ void combine_l_kernel(const float* __restrict__ lpart, float* __restrict__ linv) {
  int row = blockIdx.x * 256 + threadIdx.x;
  float s = 0.f;
#pragma unroll 8
  for (int j = 0; j < 128; j++) s += lpart[(size_t)j * 8192 + row];
  linv[row] = 1.0f / s;
}

// ---------- add two fp32 partials (optionally * linv[row]) -> bf16 ----------
template <bool NORM>
__global__ void addcvt_kernel(const float* __restrict__ a, const float* __restrict__ b,
                              const float* __restrict__ linv,
                              unsigned short* __restrict__ o, int n4) {
  int i = blockIdx.x * blockDim.x + threadIdx.x;
  int stride = gridDim.x * blockDim.x;
  for (; i < n4; i += stride) {
    float inv = NORM ? linv[i >> 7] : 1.0f;
    float4 va = ((const float4*)a)[i];
    float4 vb = ((const float4*)b)[i];
    ushort4 ov;
    ov.x = f2bf((va.x + vb.x) * inv); ov.y = f2bf((va.y + vb.y) * inv);
    ov.z = f2bf((va.z + vb.z) * inv); ov.w = f2bf((va.w + vb.w) * inv);
    ((ushort4*)o)[i] = ov;
  }
}

// ---------- deep fallback: flash attention ----------
__global__ __launch_bounds__(256, 2) void flash_kernel(
    const unsigned short* __restrict__ Q, const unsigned short* __restrict__ Kb,
    const unsigned short* __restrict__ VT, float* __restrict__ Pout,
    float* __restrict__ ML, int nsLog2) {
  __shared__ __align__(16) unsigned short k_lds[2][32][512];
  __shared__ __align__(16) unsigned short p_lds[4][16][32];
  const int tid = threadIdx.x;
  const int lane = tid & 63, w = tid >> 6;
  const int g = lane >> 4, r = lane & 15;
  const int ns = 1 << nsLog2;
  const int split = blockIdx.x & (ns - 1);
  const int qblk = blockIdx.x >> nsLog2;
  const int qbase = qblk * 64 + w * 16;
  const int kvlen = 8192 >> nsLog2;
  const int kv0 = split * kvlen;
  const int nsteps = kvlen >> 5;
  sh8 qa[16];
#pragma unroll
  for (int dc = 0; dc < 16; dc++)
    qa[dc] = *(const sh8*)&Q[(qbase + r) * 512 + dc * 32 + g * 8];
  f32x4 acc[32] = {};
  float mrow = -1e30f, lrow = 0.f;
  const float K2r = 0.04419417382415922f * 1.4426950408889634f;
#pragma unroll
  for (int ii = 0; ii < 8; ii++) {
    int row = w * 8 + ii;
    gll16(Kb + (size_t)(kv0 + row) * 512 + (size_t)((lane ^ ii) * 8), &k_lds[0][row][0]);
  }
  int cur = 0;
  const int swz = (r & 7) * 8;
  for (int s = 0; s < nsteps; s++) {
    const int kvrow0 = kv0 + s * 32;
    asm volatile("s_waitcnt vmcnt(0)" ::: "memory");
    __syncthreads();
    if (s + 1 < nsteps) {
#pragma unroll
      for (int ii = 0; ii < 8; ii++) {
        int row = w * 8 + ii;
        gll16(Kb + (size_t)(kvrow0 + 32 + row) * 512 + (size_t)((lane ^ ii) * 8),
              &k_lds[cur ^ 1][row][0]);
      }
    }
    f32x4 sA0 = {0.f, 0.f, 0.f, 0.f};
    f32x4 sA1 = {0.f, 0.f, 0.f, 0.f};
#pragma unroll
    for (int dc = 0; dc < 16; dc++) {
      int co = (dc * 32 + g * 8) ^ swz;
      sh8 kf0 = *(const sh8*)&k_lds[cur][r][co];
      sh8 kf1 = *(const sh8*)&k_lds[cur][16 + r][co];
      sA0 = mfma16(kf0, qa[dc], sA0);
      sA1 = mfma16(kf1, qa[dc], sA1);
    }
    float rmax = fmaxf(fmaxf(fmaxf(sA0[0], sA0[1]), fmaxf(sA0[2], sA0[3])),
                       fmaxf(fmaxf(sA1[0], sA1[1]), fmaxf(sA1[2], sA1[3])));
    rmax = fmaxf(rmax, __shfl_xor(rmax, 16));
    rmax = fmaxf(rmax, __shfl_xor(rmax, 32));
    float tmax = rmax * K2r;
    if (__any(tmax > mrow + 4.0f)) {
      float mn = fmaxf(mrow, tmax);
      float corr = __builtin_amdgcn_exp2f(mrow - mn);
      mrow = mn;
      lrow *= corr;
      f32x4 cv;
      cv[0] = __shfl(corr, 4 * g + 0);
      cv[1] = __shfl(corr, 4 * g + 1);
      cv[2] = __shfl(corr, 4 * g + 2);
      cv[3] = __shfl(corr, 4 * g + 3);
#pragma unroll
      for (int dt = 0; dt < 32; dt++) acc[dt] *= cv;
    }
    float p0 = __builtin_amdgcn_exp2f(fmaf(sA0[0], K2r, -mrow));
    float p1 = __builtin_amdgcn_exp2f(fmaf(sA0[1], K2r, -mrow));
    float p2 = __builtin_amdgcn_exp2f(fmaf(sA0[2], K2r, -mrow));
    float p3 = __builtin_amdgcn_exp2f(fmaf(sA0[3], K2r, -mrow));
    float p4 = __builtin_amdgcn_exp2f(fmaf(sA1[0], K2r, -mrow));
    float p5 = __builtin_amdgcn_exp2f(fmaf(sA1[1], K2r, -mrow));
    float p6 = __builtin_amdgcn_exp2f(fmaf(sA1[2], K2r, -mrow));
    float p7 = __builtin_amdgcn_exp2f(fmaf(sA1[3], K2r, -mrow));
    float ps = ((p0 + p1) + (p2 + p3)) + ((p4 + p5) + (p6 + p7));
    ps += __shfl_xor(ps, 16);
    ps += __shfl_xor(ps, 32);
    lrow += ps;
    uint2 w0, w1;
    w0.x = cvtpk(p0, p1); w0.y = cvtpk(p2, p3);
    w1.x = cvtpk(p4, p5); w1.y = cvtpk(p6, p7);
    *(uint2*)&p_lds[w][r][4 * g] = w0;
    *(uint2*)&p_lds[w][r][16 + 4 * g] = w1;
    sh8 pf = *(const sh8*)&p_lds[w][r][8 * g];
#pragma unroll
    for (int dt = 0; dt < 32; dt++) {
      sh8 vf = *(const sh8*)&VT[(dt * 16 + r) * 8192 + kvrow0 + g * 8];
      acc[dt] = mfma16(pf, vf, acc[dt]);
    }
    cur ^= 1;
  }
  float* P = Pout + (size_t)split * 4194304;
#pragma unroll
  for (int dt = 0; dt < 32; dt++)
#pragma unroll
    for (int i = 0; i < 4; i++)
      P[(qbase + 4 * g + i) * 512 + dt * 16 + r] = acc[dt][i];
  if (g == 0) {
    ML[(split * 2 + 0) * 8192 + qbase + r] = mrow;
    ML[(split * 2 + 1) * 8192 + qbase + r] = lrow;
  }
}

template <int NS>
__global__ void combine_kernel(const float* __restrict__ Pp, const float* __restrict__ ML,
                               unsigned short* __restrict__ att) {
  int idx = blockIdx.x * blockDim.x + threadIdx.x;
  int stride = gridDim.x * blockDim.x;
  for (int i4 = idx; i4 < 8192 * 512 / 4; i4 += stride) {
    int row = i4 >> 7;
    float m[NS], l[NS], e[NS];
    float mm = -1e30f;
#pragma unroll
    for (int s2 = 0; s2 < NS; s2++) {
      m[s2] = ML[(s2 * 2 + 0) * 8192 + row];
      l[s2] = ML[(s2 * 2 + 1) * 8192 + row];
      mm = fmaxf(mm, m[s2]);
    }
    float den = 0.f;
#pragma unroll
    for (int s2 = 0; s2 < NS; s2++) {
      e[s2] = __builtin_amdgcn_exp2f(m[s2] - mm);
      den += l[s2] * e[s2];
    }
    float inv = 1.0f / den;
    float ox = 0.f, oy = 0.f, oz = 0.f, ow = 0.f;
#pragma unroll
    for (int s2 = 0; s2 < NS; s2++) {
      float4 a = ((const float4*)(Pp + (size_t)s2 * 4194304))[i4];
      ox += a.x * e[s2]; oy += a.y * e[s2]; oz += a.z * e[s2]; ow += a.w * e[s2];
    }
    ushort4 ov;
    ov.x = f2bf(ox * inv); ov.y = f2bf(oy * inv);
    ov.z = f2bf(oz * inv); ov.w = f2bf(ow * inv);
    ((ushort4*)att)[i4] = ov;
  }
}

// ---------- launch ----------
extern "C" void kernel_launch(void* const* d_in, const int* in_sizes, int n_in,
                              void* d_out, int out_size, void* d_ws, size_t ws_size,
                              hipStream_t stream) {
  const float* x  = (const float*)d_in[0];
  const float* Wq = (const float*)d_in[1];
  const float* bq = (const float*)d_in[2];
  const float* Wk = (const float*)d_in[3];
  const float* bk = (const float*)d_in[4];
  const float* Wv = (const float*)d_in[5];
  const float* bv = (const float*)d_in[6];
  const float* Wo = (const float*)d_in[7];
  const float* bo = (const float*)d_in[8];
  char* ws = (char*)d_ws;

  if (ws_size >= 165707776ull) {
    // ---- Path A2: GEMM attention, softmax fused into U-GEMM epilogue ----
    unsigned short* U   = (unsigned short*)(ws + 0);          // 134.2 MB
    unsigned short* xb  = (unsigned short*)(ws + 0);          // overlay
    unsigned short* vb  = (unsigned short*)(ws + 8388608);    // overlay
    unsigned short* att = (unsigned short*)(ws + 0);          // overlay (after PV)
    unsigned short* qb  = (unsigned short*)(ws + 134217728);
    unsigned short* kb  = (unsigned short*)(ws + 142606336);
    unsigned short* vtb = (unsigned short*)(ws + 150994944);
    unsigned short* wqT = (unsigned short*)(ws + 159383552);
    unsigned short* wkT = (unsigned short*)(ws + 159907840);
    unsigned short* wvT = (unsigned short*)(ws + 160432128);
    unsigned short* woT = (unsigned short*)(ws + 160956416);
    float* lpart = (float*)(ws + 161480704);                  // 4 MB [128][8192]
    float* linv  = (float*)(ws + 165675008);                  // 32 KB
    float* P0 = (float*)qb;
    float* P1 = (float*)d_out;

    cvt_x_kernel<<<2048, 256, 0, stream>>>(x, xb, 8192 * 512 / 4);
    cvt_wT_kernel<<<dim3(16, 16, 4), 256, 0, stream>>>(Wq, Wk, Wv, Wo, wqT, wkT, wvT, woT);
    gemm_qkv_kernel<<<dim3(64, 4, 3), 256, 0, stream>>>(
        xb, wqT, wkT, wvT, bq, bk, bv, qb, kb, vb);
    transpose_v_kernel<<<dim3(16, 256), 256, 0, stream>>>(vb, vtb);
    gemm256_u_kernel<<<1024, 512, 0, stream>>>(qb, kb, U, lpart);
    combine_l_kernel<<<32, 256, 0, stream>>>(lpart, linv);
    gemm_pv_kernel<<<512, 256, 0, stream>>>(U, vtb, P0, P1);
    addcvt_kernel<true><<<2048, 256, 0, stream>>>(P0, P1, linv, att, 8192 * 512 / 4);
    gemm_o_kernel<<<dim3(64, 4), 256, 0, stream>>>(att, woT, bo, (float*)d_out);
  } else {
    // ---- Path B: flash fallback ----
    unsigned short* xb  = (unsigned short*)(ws + 0);
    unsigned short* qb  = (unsigned short*)(ws + 8388608);
    unsigned short* kb  = (unsigned short*)(ws + 16777216);
    unsigned short* vb  = (unsigned short*)(ws + 25165824);
    unsigned short* vtb = (unsigned short*)(ws + 33554432);
    unsigned short* att = (unsigned short*)(ws + 41943040);
    unsigned short* wqT = (unsigned short*)(ws + 50331648);
    unsigned short* wkT = (unsigned short*)(ws + 50855936);
    unsigned short* wvT = (unsigned short*)(ws + 51380224);
    unsigned short* woT = (unsigned short*)(ws + 51904512);
    float* ml   = (float*)(ws + 52428800);
    float* part = (float*)(ws + 52690944);
    int nsLog2 = (ws_size >= 119900000ull) ? 2 : 1;
    int NS = 1 << nsLog2;

    cvt_x_kernel<<<2048, 256, 0, stream>>>(x, xb, 8192 * 512 / 4);
    cvt_wT_kernel<<<dim3(16, 16, 4), 256, 0, stream>>>(Wq, Wk, Wv, Wo, wqT, wkT, wvT, woT);
    gemm_qkv_kernel<<<dim3(64, 4, 3), 256, 0, stream>>>(
        xb, wqT, wkT, wvT, bq, bk, bv, qb, kb, vb);
    transpose_v_kernel<<<dim3(16, 256), 256, 0, stream>>>(vb, vtb);
    flash_kernel<<<128 * NS, 256, 0, stream>>>(qb, kb, vtb, part, ml, nsLog2);
    if (NS == 4) combine_kernel<4><<<1024, 256, 0, stream>>>(part, ml, att);
    else         combine_kernel<2><<<1024, 256, 0, stream>>>(part, ml, att);
    gemm_o_kernel<<<dim3(64, 4), 256, 0, stream>>>(att, woT, bo, (float*)d_out);
  }
}

// Round 9
// 252.343 us; speedup vs baseline: 1.0313x; 1.0313x over previous
//
#include <hip/hip_runtime.h>

// ---------- common ----------
typedef short sh8 __attribute__((ext_vector_type(8)));
typedef float f32x4 __attribute__((ext_vector_type(4)));

#define DEV __device__ __forceinline__

DEV f32x4 mfma16(sh8 a, sh8 b, f32x4 c) {
  return __builtin_amdgcn_mfma_f32_16x16x32_bf16(a, b, c, 0, 0, 0);
}

DEV unsigned short f2bf(float f) {
  unsigned u = __float_as_uint(f);
  u = u + 0x7FFFu + ((u >> 16) & 1u);   // RNE
  return (unsigned short)(u >> 16);
}

DEV unsigned cvtpk(float lo, float hi) {
  unsigned r;
  asm("v_cvt_pk_bf16_f32 %0, %1, %2" : "=v"(r) : "v"(lo), "v"(hi));
  return r;
}

DEV void gll16(const void* g, void* l) {
  __builtin_amdgcn_global_load_lds(
      (const __attribute__((address_space(1))) unsigned int*)g,
      (__attribute__((address_space(3))) unsigned int*)l, 16, 0, 0);
}

// ---------- kernel: x fp32 -> bf16 ----------
__global__ void cvt_x_kernel(const float* __restrict__ x, unsigned short* __restrict__ xb, int n4) {
  int i = blockIdx.x * blockDim.x + threadIdx.x;
  int stride = gridDim.x * blockDim.x;
  for (; i < n4; i += stride) {
    float4 v = ((const float4*)x)[i];
    ushort4 o;
    o.x = f2bf(v.x); o.y = f2bf(v.y); o.z = f2bf(v.z); o.w = f2bf(v.w);
    ((ushort4*)xb)[i] = o;
  }
}

// ---------- kernel: weight transpose + cvt ----------
__global__ void cvt_wT_kernel(const float* __restrict__ W0, const float* __restrict__ W1,
                              const float* __restrict__ W2, const float* __restrict__ W3,
                              unsigned short* __restrict__ T0, unsigned short* __restrict__ T1,
                              unsigned short* __restrict__ T2, unsigned short* __restrict__ T3) {
  const float* W; unsigned short* T;
  switch (blockIdx.z) {
    case 0: W = W0; T = T0; break;
    case 1: W = W1; T = T1; break;
    case 2: W = W2; T = T2; break;
    default: W = W3; T = T3; break;
  }
  __shared__ float tile[32][33];
  int tx = threadIdx.x & 31, ty = threadIdx.x >> 5;
  int r0 = blockIdx.y * 32, c0 = blockIdx.x * 32;
#pragma unroll
  for (int i = 0; i < 4; i++) tile[ty + i * 8][tx] = W[(r0 + ty + i * 8) * 512 + c0 + tx];
  __syncthreads();
#pragma unroll
  for (int i = 0; i < 4; i++) T[(c0 + ty + i * 8) * 512 + r0 + tx] = f2bf(tile[tx][ty + i * 8]);
}

// ================= 256x256 U-GEMM, frag-carrying 4-phase schedule =================
// U = exp2(scale * Q @ K^T) + per-row partial sums. 8 waves (wm2 x wn4),
// wave tile 128x64 = 8m x 4n frags, grouped mh/nh halves.
// Per K-tile (BK=64), 4 phases:
//   ph1: ds_read a0(8)+b0(4) | stage A0(t+1) | vmcnt(2) | bar | mfma(0,0) | bar
//   ph2: ds_read b1(4)       | stage A1      |          | bar | mfma(0,1) | bar
//   ph3: ds_read a1(8)       | stage B0      |          | bar | mfma(1,0) | bar
//   ph4: (no reads)          | stage B1      | vmcnt(2) | bar | mfma(1,1) | bar
// vmcnt(2) at ph4 gates {A0,A1,B0}(t+1); at ph1 gates B1(t+1). Loads stay
// 2-4 phases in flight; only prologue/tail drain to 0.
__global__ __launch_bounds__(512, 2) void gemm256_u_kernel(
    const unsigned short* __restrict__ Q, const unsigned short* __restrict__ Kb,
    unsigned short* __restrict__ U, float* __restrict__ lpart) {
  __shared__ __align__(16) unsigned short smem[65536];
  const int tid = threadIdx.x, lane = tid & 63;
  const int w = tid >> 6;
  const int g = lane >> 4, r = lane & 15;
  const int wm2 = w & 1, wn4 = w >> 1;
  const int wgid = (blockIdx.x & 7) * 128 + (blockIdx.x >> 3);  // XCD swizzle (1024%8==0)
  const int brow = (wgid >> 5) * 256;
  const int bcol = (wgid & 31) * 256;
  const int srow = tid >> 3;      // staging row 0..63
  const int sg = tid & 7;         // staging granule

  f32x4 acc[2][2][4][2] = {};

  // stage ONE half-tile: a (0=A from Q, 1=B from Kb), half h, buf b, k-tile kt
#define STG(b, a, h, kt)                                                                       \
  do {                                                                                         \
    const unsigned short* _src = (a) ? Kb : Q;                                                 \
    int _base = (a) ? bcol : brow;                                                             \
    int _r0 = (h) * 128 + srow;                                                                \
    int _r1 = _r0 + 64;                                                                        \
    unsigned short* _d = smem + (b) * 32768 + (a) * 16384 + (h) * 8192 + tid * 8;              \
    gll16(_src + (size_t)(_base + _r0) * 512 + (kt) * 64 + ((sg ^ (_r0 & 7)) * 8), _d);        \
    gll16(_src + (size_t)(_base + _r1) * 512 + (kt) * 64 + ((sg ^ (_r1 & 7)) * 8), _d + 4096); \
  } while (0)

  auto LDA = [&](sh8 (&af)[2][4], int B_, int mh) {
    const unsigned short* As = smem + B_ * 32768;
#pragma unroll
    for (int kk = 0; kk < 2; kk++)
#pragma unroll
      for (int m = 0; m < 4; m++) {
        int row = mh * 128 + wm2 * 64 + m * 16 + r;
        af[kk][m] = *(const sh8*)&As[row * 64 + (((kk * 4 + g) ^ (r & 7)) * 8)];
      }
  };
  auto LDB = [&](sh8 (&bf)[2][2], int B_, int nh) {
    const unsigned short* Bs = smem + B_ * 32768 + 16384;
#pragma unroll
    for (int kk = 0; kk < 2; kk++)
#pragma unroll
      for (int n = 0; n < 2; n++) {
        int row = nh * 128 + wn4 * 32 + n * 16 + r;
        bf[kk][n] = *(const sh8*)&Bs[row * 64 + (((kk * 4 + g) ^ (r & 7)) * 8)];
      }
  };
  auto MM = [&](f32x4 (&c)[4][2], sh8 (&af)[2][4], sh8 (&bf)[2][2]) {
    __builtin_amdgcn_s_setprio(1);
#pragma unroll
    for (int kk = 0; kk < 2; kk++)
#pragma unroll
      for (int m = 0; m < 4; m++)
#pragma unroll
        for (int n = 0; n < 2; n++)
          c[m][n] = mfma16(af[kk][m], bf[kk][n], c[m][n]);
    __builtin_amdgcn_s_setprio(0);
  };
#define BAR asm volatile("s_barrier" ::: "memory")
#define VM2 asm volatile("s_waitcnt vmcnt(2)" ::: "memory")

  // prologue: stage tile0 fully, drain, publish
  STG(0, 0, 0, 0); STG(0, 0, 1, 0); STG(0, 1, 0, 0); STG(0, 1, 1, 0);
  asm volatile("s_waitcnt vmcnt(0)" ::: "memory");
  BAR;

#pragma unroll
  for (int kt = 0; kt < 8; ++kt) {
    const int cur = kt & 1, nb = cur ^ 1;
    const int kn = (kt < 7) ? kt + 1 : 7;   // tail: redundant restage keeps counts uniform
    sh8 a0[2][4], a1[2][4], b0[2][2], b1[2][2];
    // ph1
    LDA(a0, cur, 0); LDB(b0, cur, 0);
    STG(nb, 0, 0, kn);
    VM2; BAR;
    MM(acc[0][0], a0, b0);
    BAR;
    // ph2
    LDB(b1, cur, 1);
    STG(nb, 0, 1, kn);
    BAR;
    MM(acc[0][1], a0, b1);
    BAR;
    // ph3
    LDA(a1, cur, 1);
    STG(nb, 1, 0, kn);
    BAR;
    MM(acc[1][0], a1, b0);
    BAR;
    // ph4
    STG(nb, 1, 1, kn);
    VM2; BAR;
    MM(acc[1][1], a1, b1);
    BAR;
  }
#undef STG
#undef BAR
#undef VM2

  asm volatile("s_waitcnt vmcnt(0)" ::: "memory");
  __syncthreads();

  // epilogue: exp2, per-row partial sums, swizzled LDS restage, coalesced store
  const float K2c = 0.04419417382415922f * 1.4426950408889634f;  // 1/sqrt(512)*log2e
#pragma unroll
  for (int mh = 0; mh < 2; mh++)
#pragma unroll
    for (int m = 0; m < 4; m++)
#pragma unroll
      for (int i = 0; i < 4; i++) {
        int row = mh * 128 + wm2 * 64 + m * 16 + 4 * g + i;
        float s = 0.f;
#pragma unroll
        for (int nh = 0; nh < 2; nh++)
#pragma unroll
          for (int n = 0; n < 2; n++) {
            float v = __builtin_amdgcn_exp2f(acc[mh][nh][m][n][i] * K2c);
            s += v;
            int col = nh * 128 + wn4 * 32 + n * 16 + r;
            smem[row * 256 + (col ^ ((row & 7) << 3))] = f2bf(v);
          }
        s += __shfl_xor(s, 1); s += __shfl_xor(s, 2);
        s += __shfl_xor(s, 4); s += __shfl_xor(s, 8);
        if (r == 0)
          lpart[(size_t)((bcol >> 6) + wn4) * 8192 + brow + row] = s;
      }
  __syncthreads();
#pragma unroll
  for (int jj = 0; jj < 16; jj++) {
    int row = jj * 16 + (tid >> 5);
    int g32 = tid & 31;
    uint4 v = *(const uint4*)&smem[row * 256 + ((g32 ^ (row & 7)) * 8)];
    *(uint4*)&U[(size_t)(brow + row) * 8192 + bcol + g32 * 8] = v;
  }
}

// ---------- 128x128 GEMM core (BK=64, dbuf + counted vmcnt) ----------
template <int MODE>
DEV void gemm_core(const unsigned short* __restrict__ A, int lda,
                   const unsigned short* __restrict__ Bt, int ldb,
                   const float* __restrict__ bias, void* __restrict__ Cv, int ldc,
                   int kSteps, int koff, int brow, int bcol,
                   float* __restrict__ lpart, unsigned short* smem) {
  const int tid = threadIdx.x, lane = tid & 63, w = tid >> 6;
  const int g = lane >> 4, r = lane & 15;
  const int wr = w >> 1, wc = w & 1;
  const int rA = w * 8 + (lane >> 3);
  const int sgl = lane & 7;
  const int scol = ((sgl ^ (lane >> 3)) * 8);
  const unsigned short* aP = A + (size_t)(brow + rA) * lda + koff + scol;
  const unsigned short* bP = Bt + (size_t)(bcol + rA) * ldb + koff + scol;
  const int lOff = rA * 64 + sgl * 8;
  f32x4 acc[4][4] = {};
  const int fr = r & 7;

  auto STAGE = [&](int buf, int ks) {
    unsigned short* lA = smem + buf * 16384 + lOff;
    unsigned short* lB = smem + buf * 16384 + 8192 + lOff;
    const size_t ko = (size_t)ks * 64;
#pragma unroll
    for (int cc = 0; cc < 4; cc++) gll16(aP + (size_t)cc * 32 * lda + ko, lA + cc * 32 * 64);
#pragma unroll
    for (int cc = 0; cc < 4; cc++) gll16(bP + (size_t)cc * 32 * ldb + ko, lB + cc * 32 * 64);
  };
  auto COMPUTE = [&](int buf) {
    const unsigned short* As = smem + buf * 16384;
    const unsigned short* Bs = As + 8192;
#pragma unroll
    for (int kk = 0; kk < 2; kk++) {
      sh8 af[4], bfr[4];
#pragma unroll
      for (int m = 0; m < 4; m++)
        af[m] = *(const sh8*)&As[(wr * 64 + m * 16 + r) * 64 + (((kk * 4 + g) ^ fr) * 8)];
#pragma unroll
      for (int n = 0; n < 4; n++)
        bfr[n] = *(const sh8*)&Bs[(wc * 64 + n * 16 + r) * 64 + (((kk * 4 + g) ^ fr) * 8)];
#pragma unroll
      for (int m = 0; m < 4; m++)
#pragma unroll
        for (int n = 0; n < 4; n++) acc[m][n] = mfma16(af[m], bfr[n], acc[m][n]);
    }
  };

  STAGE(0, 0);
  int cur = 0;
  for (int ks = 0; ks + 1 < kSteps; ks++) {
    STAGE(cur ^ 1, ks + 1);
    asm volatile("s_waitcnt vmcnt(8)" ::: "memory");
    asm volatile("s_barrier" ::: "memory");
    COMPUTE(cur);
    asm volatile("s_barrier" ::: "memory");
    cur ^= 1;
  }
  asm volatile("s_waitcnt vmcnt(0)" ::: "memory");
  asm volatile("s_barrier" ::: "memory");
  COMPUTE(cur);

  if (MODE == 0) {
#pragma unroll
    for (int n = 0; n < 4; n++) {
      int col = bcol + wc * 64 + n * 16 + r;
      float bv = bias ? bias[col] : 0.f;
#pragma unroll
      for (int m = 0; m < 4; m++) {
        int row = brow + wr * 64 + m * 16 + g * 4;
#pragma unroll
        for (int i = 0; i < 4; i++)
          ((float*)Cv)[(size_t)(row + i) * ldc + col] = acc[m][n][i] + bv;
      }
    }
  } else {
    __syncthreads();
#pragma unroll
    for (int m = 0; m < 4; m++) {
#pragma unroll
      for (int n = 0; n < 4; n++) {
        int coll = wc * 64 + n * 16 + r;
        float bv = bias ? bias[bcol + coll] : 0.f;
        int rb = (wr * 64 + m * 16 + g * 4) * 132 + coll;
        smem[rb] = f2bf(acc[m][n][0] + bv);
        smem[rb + 132] = f2bf(acc[m][n][1] + bv);
        smem[rb + 264] = f2bf(acc[m][n][2] + bv);
        smem[rb + 396] = f2bf(acc[m][n][3] + bv);
      }
    }
    __syncthreads();
    unsigned short* C = (unsigned short*)Cv;
#pragma unroll
    for (int j = 0; j < 8; j++) {
      int row = w * 32 + j * 4 + (lane >> 4);
      int colb = (lane & 15) * 8;
      uint4 v = *(const uint4*)&smem[row * 132 + colb];
      *(uint4*)&C[(size_t)(brow + row) * ldc + bcol + colb] = v;
    }
  }
}

// ---------- GEMM wrappers ----------
__global__ __launch_bounds__(256, 2) void gemm_qkv_kernel(
    const unsigned short* __restrict__ A,
    const unsigned short* __restrict__ B0, const unsigned short* __restrict__ B1,
    const unsigned short* __restrict__ B2,
    const float* __restrict__ c0, const float* __restrict__ c1, const float* __restrict__ c2,
    unsigned short* __restrict__ C0, unsigned short* __restrict__ C1,
    unsigned short* __restrict__ C2) {
  __shared__ __align__(16) unsigned short smem[32768];
  const unsigned short* Bt; const float* bias; unsigned short* C;
  switch (blockIdx.z) {
    case 0: Bt = B0; bias = c0; C = C0; break;
    case 1: Bt = B1; bias = c1; C = C1; break;
    default: Bt = B2; bias = c2; C = C2; break;
  }
  gemm_core<1>(A, 512, Bt, 512, bias, C, 512, 8, 0,
               blockIdx.x * 128, blockIdx.y * 128, nullptr, smem);
}

// PV: 1-D grid of 512; c=bid&7 pins (x-tile, k-split) to an XCD for VT L2 reuse.
__global__ __launch_bounds__(256, 2) void gemm_pv_kernel(
    const unsigned short* __restrict__ U, const unsigned short* __restrict__ VT,
    float* __restrict__ P0, float* __restrict__ P1) {
  __shared__ __align__(16) unsigned short smem[32768];
  const int b = blockIdx.x;
  const int c = b & 7, xt = c & 3, zt = c >> 2, yt = b >> 3;
  float* P = zt ? P1 : P0;
  gemm_core<0>(U, 8192, VT, 8192, nullptr, P, 512, 64, zt * 4096,
               yt * 128, xt * 128, nullptr, smem);
}

__global__ __launch_bounds__(256, 2) void gemm_o_kernel(
    const unsigned short* __restrict__ att, const unsigned short* __restrict__ woT,
    const float* __restrict__ bo, float* __restrict__ out) {
  __shared__ __align__(16) unsigned short smem[32768];
  gemm_core<0>(att, 512, woT, 512, bo, out, 512, 8, 0,
               blockIdx.x * 128, blockIdx.y * 128, nullptr, smem);
}

// ---------- kernel: v [8192][512] -> vT [512][8192] (bf16) ----------
__global__ void transpose_v_kernel(const unsigned short* __restrict__ in, unsigned short* __restrict__ out) {
  __shared__ unsigned short tile[32][33];
  int tx = threadIdx.x & 31, ty = threadIdx.x >> 5;
  int r0 = blockIdx.y * 32, c0 = blockIdx.x * 32;
#pragma unroll
  for (int i = 0; i < 4; i++) tile[ty + i * 8][tx] = in[(size_t)(r0 + ty + i * 8) * 512 + c0 + tx];
  __syncthreads();
#pragma unroll
  for (int i = 0; i < 4; i++) out[(size_t)(c0 + ty + i * 8) * 8192 + r0 + tx] = tile[tx][ty + i * 8];
}

// ---------- combine row-sum partials -> 1/l ----------
__global__ void combine_l_kernel(const float* __restrict__ lpart, float* __restrict__ linv) {
  int row = blockIdx.x * 256 + threadIdx.x;
  float s = 0.f;
#pragma unroll 8
  for (int j = 0; j < 128; j++) s += lpart[(size_t)j * 8192 + row];
  linv[row] = 1.0f / s;
}

// ---------- add two fp32 partials (optionally * linv[row]) -> bf16 ----------
template <bool NORM>
__global__ void addcvt_kernel(const float* __restrict__ a, const float* __restrict__ b,
                              const float* __restrict__ linv,
                              unsigned short* __restrict__ o, int n4) {
  int i = blockIdx.x * blockDim.x + threadIdx.x;
  int stride = gridDim.x * blockDim.x;
  for (; i < n4; i += stride) {
    float inv = NORM ? linv[i >> 7] : 1.0f;
    float4 va = ((const float4*)a)[i];
    float4 vb = ((const float4*)b)[i];
    ushort4 ov;
    ov.x = f2bf((va.x + vb.x) * inv); ov.y = f2bf((va.y + vb.y) * inv);
    ov.z = f2bf((va.z + vb.z) * inv); ov.w = f2bf((va.w + vb.w) * inv);
    ((ushort4*)o)[i] = ov;
  }
}

// ---------- deep fallback: flash attention ----------
__global__ __launch_bounds__(256, 2) void flash_kernel(
    const unsigned short* __restrict__ Q, const unsigned short* __restrict__ Kb,
    const unsigned short* __restrict__ VT, float* __restrict__ Pout,
    float* __restrict__ ML, int nsLog2) {
  __shared__ __align__(16) unsigned short k_lds[2][32][512];
  __shared__ __align__(16) unsigned short p_lds[4][16][32];
  const int tid = threadIdx.x;
  const int lane = tid & 63, w = tid >> 6;
  const int g = lane >> 4, r = lane & 15;
  const int ns = 1 << nsLog2;
  const int split = blockIdx.x & (ns - 1);
  const int qblk = blockIdx.x >> nsLog2;
  const int qbase = qblk * 64 + w * 16;
  const int kvlen = 8192 >> nsLog2;
  const int kv0 = split * kvlen;
  const int nsteps = kvlen >> 5;
  sh8 qa[16];
#pragma unroll
  for (int dc = 0; dc < 16; dc++)
    qa[dc] = *(const sh8*)&Q[(qbase + r) * 512 + dc * 32 + g * 8];
  f32x4 acc[32] = {};
  float mrow = -1e30f, lrow = 0.f;
  const float K2r = 0.04419417382415922f * 1.4426950408889634f;
#pragma unroll
  for (int ii = 0; ii < 8; ii++) {
    int row = w * 8 + ii;
    gll16(Kb + (size_t)(kv0 + row) * 512 + (size_t)((lane ^ ii) * 8), &k_lds[0][row][0]);
  }
  int cur = 0;
  const int swz = (r & 7) * 8;
  for (int s = 0; s < nsteps; s++) {
    const int kvrow0 = kv0 + s * 32;
    asm volatile("s_waitcnt vmcnt(0)" ::: "memory");
    __syncthreads();
    if (s + 1 < nsteps) {
#pragma unroll
      for (int ii = 0; ii < 8; ii++) {
        int row = w * 8 + ii;
        gll16(Kb + (size_t)(kvrow0 + 32 + row) * 512 + (size_t)((lane ^ ii) * 8),
              &k_lds[cur ^ 1][row][0]);
      }
    }
    f32x4 sA0 = {0.f, 0.f, 0.f, 0.f};
    f32x4 sA1 = {0.f, 0.f, 0.f, 0.f};
#pragma unroll
    for (int dc = 0; dc < 16; dc++) {
      int co = (dc * 32 + g * 8) ^ swz;
      sh8 kf0 = *(const sh8*)&k_lds[cur][r][co];
      sh8 kf1 = *(const sh8*)&k_lds[cur][16 + r][co];
      sA0 = mfma16(kf0, qa[dc], sA0);
      sA1 = mfma16(kf1, qa[dc], sA1);
    }
    float rmax = fmaxf(fmaxf(fmaxf(sA0[0], sA0[1]), fmaxf(sA0[2], sA0[3])),
                       fmaxf(fmaxf(sA1[0], sA1[1]), fmaxf(sA1[2], sA1[3])));
    rmax = fmaxf(rmax, __shfl_xor(rmax, 16));
    rmax = fmaxf(rmax, __shfl_xor(rmax, 32));
    float tmax = rmax * K2r;
    if (__any(tmax > mrow + 4.0f)) {
      float mn = fmaxf(mrow, tmax);
      float corr = __builtin_amdgcn_exp2f(mrow - mn);
      mrow = mn;
      lrow *= corr;
      f32x4 cv;
      cv[0] = __shfl(corr, 4 * g + 0);
      cv[1] = __shfl(corr, 4 * g + 1);
      cv[2] = __shfl(corr, 4 * g + 2);
      cv[3] = __shfl(corr, 4 * g + 3);
#pragma unroll
      for (int dt = 0; dt < 32; dt++) acc[dt] *= cv;
    }
    float p0 = __builtin_amdgcn_exp2f(fmaf(sA0[0], K2r, -mrow));
    float p1 = __builtin_amdgcn_exp2f(fmaf(sA0[1], K2r, -mrow));
    float p2 = __builtin_amdgcn_exp2f(fmaf(sA0[2], K2r, -mrow));
    float p3 = __builtin_amdgcn_exp2f(fmaf(sA0[3], K2r, -mrow));
    float p4 = __builtin_amdgcn_exp2f(fmaf(sA1[0], K2r, -mrow));
    float p5 = __builtin_amdgcn_exp2f(fmaf(sA1[1], K2r, -mrow));
    float p6 = __builtin_amdgcn_exp2f(fmaf(sA1[2], K2r, -mrow));
    float p7 = __builtin_amdgcn_exp2f(fmaf(sA1[3], K2r, -mrow));
    float ps = ((p0 + p1) + (p2 + p3)) + ((p4 + p5) + (p6 + p7));
    ps += __shfl_xor(ps, 16);
    ps += __shfl_xor(ps, 32);
    lrow += ps;
    uint2 w0, w1;
    w0.x = cvtpk(p0, p1); w0.y = cvtpk(p2, p3);
    w1.x = cvtpk(p4, p5); w1.y = cvtpk(p6, p7);
    *(uint2*)&p_lds[w][r][4 * g] = w0;
    *(uint2*)&p_lds[w][r][16 + 4 * g] = w1;
    sh8 pf = *(const sh8*)&p_lds[w][r][8 * g];
#pragma unroll
    for (int dt = 0; dt < 32; dt++) {
      sh8 vf = *(const sh8*)&VT[(dt * 16 + r) * 8192 + kvrow0 + g * 8];
      acc[dt] = mfma16(pf, vf, acc[dt]);
    }
    cur ^= 1;
  }
  float* P = Pout + (size_t)split * 4194304;
#pragma unroll
  for (int dt = 0; dt < 32; dt++)
#pragma unroll
    for (int i = 0; i < 4; i++)
      P[(qbase + 4 * g + i) * 512 + dt * 16 + r] = acc[dt][i];
  if (g == 0) {
    ML[(split * 2 + 0) * 8192 + qbase + r] = mrow;
    ML[(split * 2 + 1) * 8192 + qbase + r] = lrow;
  }
}

template <int NS>
__global__ void combine_kernel(const float* __restrict__ Pp, const float* __restrict__ ML,
                               unsigned short* __restrict__ att) {
  int idx = blockIdx.x * blockDim.x + threadIdx.x;
  int stride = gridDim.x * blockDim.x;
  for (int i4 = idx; i4 < 8192 * 512 / 4; i4 += stride) {
    int row = i4 >> 7;
    float m[NS], l[NS], e[NS];
    float mm = -1e30f;
#pragma unroll
    for (int s2 = 0; s2 < NS; s2++) {
      m[s2] = ML[(s2 * 2 + 0) * 8192 + row];
      l[s2] = ML[(s2 * 2 + 1) * 8192 + row];
      mm = fmaxf(mm, m[s2]);
    }
    float den = 0.f;
#pragma unroll
    for (int s2 = 0; s2 < NS; s2++) {
      e[s2] = __builtin_amdgcn_exp2f(m[s2] - mm);
      den += l[s2] * e[s2];
    }
    float inv = 1.0f / den;
    float ox = 0.f, oy = 0.f, oz = 0.f, ow = 0.f;
#pragma unroll
    for (int s2 = 0; s2 < NS; s2++) {
      float4 a = ((const float4*)(Pp + (size_t)s2 * 4194304))[i4];
      ox += a.x * e[s2]; oy += a.y * e[s2]; oz += a.z * e[s2]; ow += a.w * e[s2];
    }
    ushort4 ov;
    ov.x = f2bf(ox * inv); ov.y = f2bf(oy * inv);
    ov.z = f2bf(oz * inv); ov.w = f2bf(ow * inv);
    ((ushort4*)att)[i4] = ov;
  }
}

// ---------- launch ----------
extern "C" void kernel_launch(void* const* d_in, const int* in_sizes, int n_in,
                              void* d_out, int out_size, void* d_ws, size_t ws_size,
                              hipStream_t stream) {
  const float* x  = (const float*)d_in[0];
  const float* Wq = (const float*)d_in[1];
  const float* bq = (const float*)d_in[2];
  const float* Wk = (const float*)d_in[3];
  const float* bk = (const float*)d_in[4];
  const float* Wv = (const float*)d_in[5];
  const float* bv = (const float*)d_in[6];
  const float* Wo = (const float*)d_in[7];
  const float* bo = (const float*)d_in[8];
  char* ws = (char*)d_ws;

  if (ws_size >= 165707776ull) {
    // ---- Path A2: GEMM attention, softmax fused into U-GEMM epilogue ----
    unsigned short* U   = (unsigned short*)(ws + 0);          // 134.2 MB
    unsigned short* xb  = (unsigned short*)(ws + 0);          // overlay
    unsigned short* vb  = (unsigned short*)(ws + 8388608);    // overlay
    unsigned short* att = (unsigned short*)(ws + 0);          // overlay (after PV)
    unsigned short* qb  = (unsigned short*)(ws + 134217728);
    unsigned short* kb  = (unsigned short*)(ws + 142606336);
    unsigned short* vtb = (unsigned short*)(ws + 150994944);
    unsigned short* wqT = (unsigned short*)(ws + 159383552);
    unsigned short* wkT = (unsigned short*)(ws + 159907840);
    unsigned short* wvT = (unsigned short*)(ws + 160432128);
    unsigned short* woT = (unsigned short*)(ws + 160956416);
    float* lpart = (float*)(ws + 161480704);                  // 4 MB [128][8192]
    float* linv  = (float*)(ws + 165675008);                  // 32 KB
    float* P0 = (float*)qb;
    float* P1 = (float*)d_out;

    cvt_x_kernel<<<2048, 256, 0, stream>>>(x, xb, 8192 * 512 / 4);
    cvt_wT_kernel<<<dim3(16, 16, 4), 256, 0, stream>>>(Wq, Wk, Wv, Wo, wqT, wkT, wvT, woT);
    gemm_qkv_kernel<<<dim3(64, 4, 3), 256, 0, stream>>>(
        xb, wqT, wkT, wvT, bq, bk, bv, qb, kb, vb);
    transpose_v_kernel<<<dim3(16, 256), 256, 0, stream>>>(vb, vtb);
    gemm256_u_kernel<<<1024, 512, 0, stream>>>(qb, kb, U, lpart);
    combine_l_kernel<<<32, 256, 0, stream>>>(lpart, linv);
    gemm_pv_kernel<<<512, 256, 0, stream>>>(U, vtb, P0, P1);
    addcvt_kernel<true><<<2048, 256, 0, stream>>>(P0, P1, linv, att, 8192 * 512 / 4);
    gemm_o_kernel<<<dim3(64, 4), 256, 0, stream>>>(att, woT, bo, (float*)d_out);
  } else {
    // ---- Path B: flash fallback ----
    unsigned short* xb  = (unsigned short*)(ws + 0);
    unsigned short* qb  = (unsigned short*)(ws + 8388608);
    unsigned short* kb  = (unsigned short*)(ws + 16777216);
    unsigned short* vb  = (unsigned short*)(ws + 25165824);
    unsigned short* vtb = (unsigned short*)(ws + 33554432);
    unsigned short* att = (unsigned short*)(ws + 41943040);
    unsigned short* wqT = (unsigned short*)(ws + 50331648);
    unsigned short* wkT = (unsigned short*)(ws + 50855936);
    unsigned short* wvT = (unsigned short*)(ws + 51380224);
    unsigned short* woT = (unsigned short*)(ws + 51904512);
    float* ml   = (float*)(ws + 52428800);
    float* part = (float*)(ws + 52690944);
    int nsLog2 = (ws_size >= 119900000ull) ? 2 : 1;
    int NS = 1 << nsLog2;

    cvt_x_kernel<<<2048, 256, 0, stream>>>(x, xb, 8192 * 512 / 4);
    cvt_wT_kernel<<<dim3(16, 16, 4), 256, 0, stream>>>(Wq, Wk, Wv, Wo, wqT, wkT, wvT, woT);
    gemm_qkv_kernel<<<dim3(64, 4, 3), 256, 0, stream>>>(
        xb, wqT, wkT, wvT, bq, bk, bv, qb, kb, vb);
    transpose_v_kernel<<<dim3(16, 256), 256, 0, stream>>>(vb, vtb);
    flash_kernel<<<128 * NS, 256, 0, stream>>>(qb, kb, vtb, part, ml, nsLog2);
    if (NS == 4) combine_kernel<4><<<1024, 256, 0, stream>>>(part, ml, att);
    else         combine_kernel<2><<<1024, 256, 0, stream>>>(part, ml, att);
    gemm_o_kernel<<<dim3(64, 4), 256, 0, stream>>>(att, woT, bo, (float*)d_out);
  }
}

// Round 10
// 234.041 us; speedup vs baseline: 1.1120x; 1.0782x over previous
//
#include <hip/hip_runtime.h>

// ---------- common ----------
typedef short sh8 __attribute__((ext_vector_type(8)));
typedef float f32x4 __attribute__((ext_vector_type(4)));

#define DEV __device__ __forceinline__

DEV f32x4 mfma16(sh8 a, sh8 b, f32x4 c) {
  return __builtin_amdgcn_mfma_f32_16x16x32_bf16(a, b, c, 0, 0, 0);
}

DEV unsigned short f2bf(float f) {
  unsigned u = __float_as_uint(f);
  u = u + 0x7FFFu + ((u >> 16) & 1u);   // RNE
  return (unsigned short)(u >> 16);
}

DEV unsigned cvtpk(float lo, float hi) {
  unsigned r;
  asm("v_cvt_pk_bf16_f32 %0, %1, %2" : "=v"(r) : "v"(lo), "v"(hi));
  return r;
}

DEV void gll16(const void* g, void* l) {
  __builtin_amdgcn_global_load_lds(
      (const __attribute__((address_space(1))) unsigned int*)g,
      (__attribute__((address_space(3))) unsigned int*)l, 16, 0, 0);
}

// ---------- kernel: x fp32 -> bf16 ----------
__global__ void cvt_x_kernel(const float* __restrict__ x, unsigned short* __restrict__ xb, int n4) {
  int i = blockIdx.x * blockDim.x + threadIdx.x;
  int stride = gridDim.x * blockDim.x;
  for (; i < n4; i += stride) {
    float4 v = ((const float4*)x)[i];
    ushort4 o;
    o.x = f2bf(v.x); o.y = f2bf(v.y); o.z = f2bf(v.z); o.w = f2bf(v.w);
    ((ushort4*)xb)[i] = o;
  }
}

// ---------- kernel: weight transpose + cvt ----------
__global__ void cvt_wT_kernel(const float* __restrict__ W0, const float* __restrict__ W1,
                              const float* __restrict__ W2, const float* __restrict__ W3,
                              unsigned short* __restrict__ T0, unsigned short* __restrict__ T1,
                              unsigned short* __restrict__ T2, unsigned short* __restrict__ T3) {
  const float* W; unsigned short* T;
  switch (blockIdx.z) {
    case 0: W = W0; T = T0; break;
    case 1: W = W1; T = T1; break;
    case 2: W = W2; T = T2; break;
    default: W = W3; T = T3; break;
  }
  __shared__ float tile[32][33];
  int tx = threadIdx.x & 31, ty = threadIdx.x >> 5;
  int r0 = blockIdx.y * 32, c0 = blockIdx.x * 32;
#pragma unroll
  for (int i = 0; i < 4; i++) tile[ty + i * 8][tx] = W[(r0 + ty + i * 8) * 512 + c0 + tx];
  __syncthreads();
#pragma unroll
  for (int i = 0; i < 4; i++) T[(c0 + ty + i * 8) * 512 + r0 + tx] = f2bf(tile[tx][ty + i * 8]);
}

// ================= 256x256 U-GEMM, swapped-operand 4-phase schedule =================
// U = exp2(scale * Q @ K^T) + per-row partial sums. SWAPPED MFMA: first
// operand = K rows (U cols), second = Q rows. Lane then holds 4 CONSECUTIVE
// k-cols of one q-row -> epilogue uses cvt_pk + ds_write_b64 (32/wave) and
// 2-shfl row sums (8/wave) instead of 128 b16-writes + 128 bpermutes.
// Wave = 64q (wn4 strip) x 128k (wm2 strip). Per K-tile (BK=64), 4 phases:
//   ph1: ds_read k0(8)+q0(4) | stage A0(t+1) | vmcnt(2) | bar | mfma(k0,q0) | bar
//   ph2: ds_read q1(4)       | stage A1      |          | bar | mfma(k0,q1) | bar
//   ph3: ds_read k1(8)       | stage B0      |          | bar | mfma(k1,q0) | bar
//   ph4: (none)              | stage B1      | vmcnt(2) | bar | mfma(k1,q1) | bar
__global__ __launch_bounds__(512, 2) void gemm256_u_kernel(
    const unsigned short* __restrict__ Q, const unsigned short* __restrict__ Kb,
    unsigned short* __restrict__ U, float* __restrict__ lpart) {
  __shared__ __align__(16) unsigned short smem[65536];
  const int tid = threadIdx.x, lane = tid & 63;
  const int w = tid >> 6;
  const int g = lane >> 4, r = lane & 15;
  const int wm2 = w & 1, wn4 = w >> 1;
  const int wgid = (blockIdx.x & 7) * 128 + (blockIdx.x >> 3);  // XCD swizzle (1024%8==0)
  const int brow = (wgid >> 5) * 256;   // q base
  const int bcol = (wgid & 31) * 256;   // k base
  const int srow = tid >> 3;            // staging row 0..63
  const int sg = tid & 7;               // staging granule

  f32x4 acc[2][2][4][2] = {};           // [kh][qh][m][n]

  // stage ONE half-tile: a (0=Q panel, 1=K panel), half h, buf b, k-tile kt
#define STG(b, a, h, kt)                                                                       \
  do {                                                                                         \
    const unsigned short* _src = (a) ? Kb : Q;                                                 \
    int _base = (a) ? bcol : brow;                                                             \
    int _r0 = (h) * 128 + srow;                                                                \
    int _r1 = _r0 + 64;                                                                        \
    unsigned short* _d = smem + (b) * 32768 + (a) * 16384 + (h) * 8192 + tid * 8;              \
    gll16(_src + (size_t)(_base + _r0) * 512 + (kt) * 64 + ((sg ^ (_r0 & 7)) * 8), _d);        \
    gll16(_src + (size_t)(_base + _r1) * 512 + (kt) * 64 + ((sg ^ (_r1 & 7)) * 8), _d + 4096); \
  } while (0)

  // first operand: K rows (U cols), 8 frags (4 m x 2 kk)
  auto LDK = [&](sh8 (&kf)[2][4], int B_, int kh) {
    const unsigned short* Bs = smem + B_ * 32768 + 16384;
#pragma unroll
    for (int kk = 0; kk < 2; kk++)
#pragma unroll
      for (int m = 0; m < 4; m++) {
        int row = kh * 128 + wm2 * 64 + m * 16 + r;
        kf[kk][m] = *(const sh8*)&Bs[row * 64 + (((kk * 4 + g) ^ (r & 7)) * 8)];
      }
  };
  // second operand: Q rows, 4 frags (2 n x 2 kk)
  auto LDQ = [&](sh8 (&qf)[2][2], int B_, int qh) {
    const unsigned short* As = smem + B_ * 32768;
#pragma unroll
    for (int kk = 0; kk < 2; kk++)
#pragma unroll
      for (int n = 0; n < 2; n++) {
        int row = qh * 128 + wn4 * 32 + n * 16 + r;
        qf[kk][n] = *(const sh8*)&As[row * 64 + (((kk * 4 + g) ^ (r & 7)) * 8)];
      }
  };
  auto MM = [&](f32x4 (&c)[4][2], sh8 (&kf)[2][4], sh8 (&qf)[2][2]) {
    __builtin_amdgcn_s_setprio(1);
#pragma unroll
    for (int kk = 0; kk < 2; kk++)
#pragma unroll
      for (int m = 0; m < 4; m++)
#pragma unroll
        for (int n = 0; n < 2; n++)
          c[m][n] = mfma16(kf[kk][m], qf[kk][n], c[m][n]);
    __builtin_amdgcn_s_setprio(0);
  };
#define BAR asm volatile("s_barrier" ::: "memory")
#define VM2 asm volatile("s_waitcnt vmcnt(2)" ::: "memory")

  // prologue: stage tile0 fully, drain, publish
  STG(0, 0, 0, 0); STG(0, 0, 1, 0); STG(0, 1, 0, 0); STG(0, 1, 1, 0);
  asm volatile("s_waitcnt vmcnt(0)" ::: "memory");
  BAR;

#pragma unroll
  for (int kt = 0; kt < 8; ++kt) {
    const int cur = kt & 1, nb = cur ^ 1;
    const int kn = (kt < 7) ? kt + 1 : 7;   // tail: redundant restage keeps counts uniform
    sh8 k0[2][4], k1[2][4], q0[2][2], q1[2][2];
    // ph1
    LDK(k0, cur, 0); LDQ(q0, cur, 0);
    STG(nb, 0, 0, kn);
    VM2; BAR;
    MM(acc[0][0], k0, q0);
    BAR;
    // ph2
    LDQ(q1, cur, 1);
    STG(nb, 0, 1, kn);
    BAR;
    MM(acc[0][1], k0, q1);
    BAR;
    // ph3
    LDK(k1, cur, 1);
    STG(nb, 1, 0, kn);
    BAR;
    MM(acc[1][0], k1, q0);
    BAR;
    // ph4
    STG(nb, 1, 1, kn);
    VM2; BAR;
    MM(acc[1][1], k1, q1);
    BAR;
  }
#undef STG
#undef BAR
#undef VM2

  asm volatile("s_waitcnt vmcnt(0)" ::: "memory");
  __syncthreads();

  // epilogue (swapped layout): per frag, lane holds U[qrow][kcol0..kcol0+3].
  // exp2 -> cvt_pk -> ds_write_b64; row sum = 32-value in-reg add + 2 shfls.
  const float K2c = 0.04419417382415922f * 1.4426950408889634f;  // 1/sqrt(512)*log2e
#pragma unroll
  for (int qh = 0; qh < 2; qh++)
#pragma unroll
    for (int n = 0; n < 2; n++) {
      int qr = qh * 128 + wn4 * 32 + n * 16 + r;   // local q row
      float s = 0.f;
#pragma unroll
      for (int kh = 0; kh < 2; kh++)
#pragma unroll
        for (int m = 0; m < 4; m++) {
          f32x4 a = acc[kh][qh][m][n];
          float v0 = __builtin_amdgcn_exp2f(a[0] * K2c);
          float v1 = __builtin_amdgcn_exp2f(a[1] * K2c);
          float v2 = __builtin_amdgcn_exp2f(a[2] * K2c);
          float v3 = __builtin_amdgcn_exp2f(a[3] * K2c);
          s += (v0 + v1) + (v2 + v3);
          uint2 pk; pk.x = cvtpk(v0, v1); pk.y = cvtpk(v2, v3);
          int ke = kh * 128 + wm2 * 64 + m * 16 + g * 4;      // elem offset in row
          int el = qr * 256 + (ke ^ ((qr & 7) * 8));          // granule-8 XOR swizzle
          *(uint2*)&smem[el] = pk;
        }
      s += __shfl_xor(s, 16);
      s += __shfl_xor(s, 32);
      if (g == 0)
        lpart[(size_t)((bcol >> 7) + wm2) * 8192 + brow + qr] = s;
    }
  __syncthreads();
#pragma unroll
  for (int jj = 0; jj < 16; jj++) {
    int row = jj * 16 + (tid >> 5);
    int g32 = tid & 31;
    uint4 v = *(const uint4*)&smem[row * 256 + ((g32 ^ (row & 7)) * 8)];
    *(uint4*)&U[(size_t)(brow + row) * 8192 + bcol + g32 * 8] = v;
  }
}

// ---------- 128x128 GEMM core (BK=64, dbuf + counted vmcnt) ----------
template <int MODE>
DEV void gemm_core(const unsigned short* __restrict__ A, int lda,
                   const unsigned short* __restrict__ Bt, int ldb,
                   const float* __restrict__ bias, void* __restrict__ Cv, int ldc,
                   int kSteps, int koff, int brow, int bcol,
                   unsigned short* smem) {
  const int tid = threadIdx.x, lane = tid & 63, w = tid >> 6;
  const int g = lane >> 4, r = lane & 15;
  const int wr = w >> 1, wc = w & 1;
  const int rA = w * 8 + (lane >> 3);
  const int sgl = lane & 7;
  const int scol = ((sgl ^ (lane >> 3)) * 8);
  const unsigned short* aP = A + (size_t)(brow + rA) * lda + koff + scol;
  const unsigned short* bP = Bt + (size_t)(bcol + rA) * ldb + koff + scol;
  const int lOff = rA * 64 + sgl * 8;
  f32x4 acc[4][4] = {};
  const int fr = r & 7;

  auto STAGE = [&](int buf, int ks) {
    unsigned short* lA = smem + buf * 16384 + lOff;
    unsigned short* lB = smem + buf * 16384 + 8192 + lOff;
    const size_t ko = (size_t)ks * 64;
#pragma unroll
    for (int cc = 0; cc < 4; cc++) gll16(aP + (size_t)cc * 32 * lda + ko, lA + cc * 32 * 64);
#pragma unroll
    for (int cc = 0; cc < 4; cc++) gll16(bP + (size_t)cc * 32 * ldb + ko, lB + cc * 32 * 64);
  };
  auto COMPUTE = [&](int buf) {
    const unsigned short* As = smem + buf * 16384;
    const unsigned short* Bs = As + 8192;
#pragma unroll
    for (int kk = 0; kk < 2; kk++) {
      sh8 af[4], bfr[4];
#pragma unroll
      for (int m = 0; m < 4; m++)
        af[m] = *(const sh8*)&As[(wr * 64 + m * 16 + r) * 64 + (((kk * 4 + g) ^ fr) * 8)];
#pragma unroll
      for (int n = 0; n < 4; n++)
        bfr[n] = *(const sh8*)&Bs[(wc * 64 + n * 16 + r) * 64 + (((kk * 4 + g) ^ fr) * 8)];
#pragma unroll
      for (int m = 0; m < 4; m++)
#pragma unroll
        for (int n = 0; n < 4; n++) acc[m][n] = mfma16(af[m], bfr[n], acc[m][n]);
    }
  };

  STAGE(0, 0);
  int cur = 0;
  for (int ks = 0; ks + 1 < kSteps; ks++) {
    STAGE(cur ^ 1, ks + 1);
    asm volatile("s_waitcnt vmcnt(8)" ::: "memory");
    asm volatile("s_barrier" ::: "memory");
    COMPUTE(cur);
    asm volatile("s_barrier" ::: "memory");
    cur ^= 1;
  }
  asm volatile("s_waitcnt vmcnt(0)" ::: "memory");
  asm volatile("s_barrier" ::: "memory");
  COMPUTE(cur);

  if (MODE == 0) {
#pragma unroll
    for (int n = 0; n < 4; n++) {
      int col = bcol + wc * 64 + n * 16 + r;
      float bv = bias ? bias[col] : 0.f;
#pragma unroll
      for (int m = 0; m < 4; m++) {
        int row = brow + wr * 64 + m * 16 + g * 4;
#pragma unroll
        for (int i = 0; i < 4; i++)
          ((float*)Cv)[(size_t)(row + i) * ldc + col] = acc[m][n][i] + bv;
      }
    }
  } else {
    __syncthreads();
#pragma unroll
    for (int m = 0; m < 4; m++) {
#pragma unroll
      for (int n = 0; n < 4; n++) {
        int coll = wc * 64 + n * 16 + r;
        float bv = bias ? bias[bcol + coll] : 0.f;
        int rb = (wr * 64 + m * 16 + g * 4) * 132 + coll;
        smem[rb] = f2bf(acc[m][n][0] + bv);
        smem[rb + 132] = f2bf(acc[m][n][1] + bv);
        smem[rb + 264] = f2bf(acc[m][n][2] + bv);
        smem[rb + 396] = f2bf(acc[m][n][3] + bv);
      }
    }
    __syncthreads();
    unsigned short* C = (unsigned short*)Cv;
#pragma unroll
    for (int j = 0; j < 8; j++) {
      int row = w * 32 + j * 4 + (lane >> 4);
      int colb = (lane & 15) * 8;
      uint4 v = *(const uint4*)&smem[row * 132 + colb];
      *(uint4*)&C[(size_t)(brow + row) * ldc + bcol + colb] = v;
    }
  }
}

// ---------- GEMM wrappers ----------
__global__ __launch_bounds__(256, 2) void gemm_qkv_kernel(
    const unsigned short* __restrict__ A,
    const unsigned short* __restrict__ B0, const unsigned short* __restrict__ B1,
    const unsigned short* __restrict__ B2,
    const float* __restrict__ c0, const float* __restrict__ c1, const float* __restrict__ c2,
    unsigned short* __restrict__ C0, unsigned short* __restrict__ C1,
    unsigned short* __restrict__ C2) {
  __shared__ __align__(16) unsigned short smem[32768];
  const unsigned short* Bt; const float* bias; unsigned short* C;
  switch (blockIdx.z) {
    case 0: Bt = B0; bias = c0; C = C0; break;
    case 1: Bt = B1; bias = c1; C = C1; break;
    default: Bt = B2; bias = c2; C = C2; break;
  }
  gemm_core<1>(A, 512, Bt, 512, bias, C, 512, 8, 0,
               blockIdx.x * 128, blockIdx.y * 128, smem);
}

// PV: 1-D grid of 512; c=bid&7 pins (x-tile, k-split) to an XCD for VT L2 reuse.
__global__ __launch_bounds__(256, 2) void gemm_pv_kernel(
    const unsigned short* __restrict__ U, const unsigned short* __restrict__ VT,
    float* __restrict__ P0, float* __restrict__ P1) {
  __shared__ __align__(16) unsigned short smem[32768];
  const int b = blockIdx.x;
  const int c = b & 7, xt = c & 3, zt = c >> 2, yt = b >> 3;
  float* P = zt ? P1 : P0;
  gemm_core<0>(U, 8192, VT, 8192, nullptr, P, 512, 64, zt * 4096,
               yt * 128, xt * 128, smem);
}

__global__ __launch_bounds__(256, 2) void gemm_o_kernel(
    const unsigned short* __restrict__ att, const unsigned short* __restrict__ woT,
    const float* __restrict__ bo, float* __restrict__ out) {
  __shared__ __align__(16) unsigned short smem[32768];
  gemm_core<0>(att, 512, woT, 512, bo, out, 512, 8, 0,
               blockIdx.x * 128, blockIdx.y * 128, smem);
}

// ---------- kernel: v [8192][512] -> vT [512][8192] (bf16) ----------
__global__ void transpose_v_kernel(const unsigned short* __restrict__ in, unsigned short* __restrict__ out) {
  __shared__ unsigned short tile[32][33];
  int tx = threadIdx.x & 31, ty = threadIdx.x >> 5;
  int r0 = blockIdx.y * 32, c0 = blockIdx.x * 32;
#pragma unroll
  for (int i = 0; i < 4; i++) tile[ty + i * 8][tx] = in[(size_t)(r0 + ty + i * 8) * 512 + c0 + tx];
  __syncthreads();
#pragma unroll
  for (int i = 0; i < 4; i++) out[(size_t)(c0 + ty + i * 8) * 8192 + r0 + tx] = tile[tx][ty + i * 8];
}

// ---------- combine row-sum partials (64 k-chunks) -> 1/l ----------
__global__ void combine_l_kernel(const float* __restrict__ lpart, float* __restrict__ linv) {
  int row = blockIdx.x * 256 + threadIdx.x;
  float s = 0.f;
#pragma unroll 8
  for (int j = 0; j < 64; j++) s += lpart[(size_t)j * 8192 + row];
  linv[row] = 1.0f / s;
}

// ---------- add two fp32 partials * linv[row] -> bf16 ----------
__global__ void addcvt_kernel(const float* __restrict__ a, const float* __restrict__ b,
                              const float* __restrict__ linv,
                              unsigned short* __restrict__ o, int n4) {
  int i = blockIdx.x * blockDim.x + threadIdx.x;
  int stride = gridDim.x * blockDim.x;
  for (; i < n4; i += stride) {
    float inv = linv[i >> 7];
    float4 va = ((const float4*)a)[i];
    float4 vb = ((const float4*)b)[i];
    ushort4 ov;
    ov.x = f2bf((va.x + vb.x) * inv); ov.y = f2bf((va.y + vb.y) * inv);
    ov.z = f2bf((va.z + vb.z) * inv); ov.w = f2bf((va.w + vb.w) * inv);
    ((ushort4*)o)[i] = ov;
  }
}

// ---------- launch ----------
extern "C" void kernel_launch(void* const* d_in, const int* in_sizes, int n_in,
                              void* d_out, int out_size, void* d_ws, size_t ws_size,
                              hipStream_t stream) {
  const float* x  = (const float*)d_in[0];
  const float* Wq = (const float*)d_in[1];
  const float* bq = (const float*)d_in[2];
  const float* Wk = (const float*)d_in[3];
  const float* bk = (const float*)d_in[4];
  const float* Wv = (const float*)d_in[5];
  const float* bv = (const float*)d_in[6];
  const float* Wo = (const float*)d_in[7];
  const float* bo = (const float*)d_in[8];
  char* ws = (char*)d_ws;

  // ---- Path A2: GEMM attention, softmax fused into U-GEMM epilogue ----
  unsigned short* U   = (unsigned short*)(ws + 0);          // 134.2 MB
  unsigned short* xb  = (unsigned short*)(ws + 0);          // overlay
  unsigned short* vb  = (unsigned short*)(ws + 8388608);    // overlay
  unsigned short* att = (unsigned short*)(ws + 0);          // overlay (after PV)
  unsigned short* qb  = (unsigned short*)(ws + 134217728);
  unsigned short* kb  = (unsigned short*)(ws + 142606336);
  unsigned short* vtb = (unsigned short*)(ws + 150994944);
  unsigned short* wqT = (unsigned short*)(ws + 159383552);
  unsigned short* wkT = (unsigned short*)(ws + 159907840);
  unsigned short* wvT = (unsigned short*)(ws + 160432128);
  unsigned short* woT = (unsigned short*)(ws + 160956416);
  float* lpart = (float*)(ws + 161480704);                  // 2 MB [64][8192]
  float* linv  = (float*)(ws + 165675008);                  // 32 KB
  float* P0 = (float*)qb;        // 16 MB over qb+kb (dead after U-GEMM)
  float* P1 = (float*)d_out;     // overwritten by O-proj

  cvt_x_kernel<<<2048, 256, 0, stream>>>(x, xb, 8192 * 512 / 4);
  cvt_wT_kernel<<<dim3(16, 16, 4), 256, 0, stream>>>(Wq, Wk, Wv, Wo, wqT, wkT, wvT, woT);
  gemm_qkv_kernel<<<dim3(64, 4, 3), 256, 0, stream>>>(
      xb, wqT, wkT, wvT, bq, bk, bv, qb, kb, vb);
  transpose_v_kernel<<<dim3(16, 256), 256, 0, stream>>>(vb, vtb);
  gemm256_u_kernel<<<1024, 512, 0, stream>>>(qb, kb, U, lpart);
  combine_l_kernel<<<32, 256, 0, stream>>>(lpart, linv);
  gemm_pv_kernel<<<512, 256, 0, stream>>>(U, vtb, P0, P1);
  addcvt_kernel<<<2048, 256, 0, stream>>>(P0, P1, linv, att, 8192 * 512 / 4);
  gemm_o_kernel<<<dim3(64, 4), 256, 0, stream>>>(att, woT, bo, (float*)d_out);
}

// Round 11
// 211.603 us; speedup vs baseline: 1.2299x; 1.1060x over previous
//
#include <hip/hip_runtime.h>

// ---------- common ----------
typedef short sh8 __attribute__((ext_vector_type(8)));
typedef float f32x4 __attribute__((ext_vector_type(4)));

#define DEV __device__ __forceinline__

DEV f32x4 mfma16(sh8 a, sh8 b, f32x4 c) {
  return __builtin_amdgcn_mfma_f32_16x16x32_bf16(a, b, c, 0, 0, 0);
}

DEV unsigned short f2bf(float f) {
  unsigned u = __float_as_uint(f);
  u = u + 0x7FFFu + ((u >> 16) & 1u);   // RNE
  return (unsigned short)(u >> 16);
}

DEV unsigned cvtpk(float lo, float hi) {
  unsigned r;
  asm("v_cvt_pk_bf16_f32 %0, %1, %2" : "=v"(r) : "v"(lo), "v"(hi));
  return r;
}

DEV void gll16(const void* g, void* l) {
  __builtin_amdgcn_global_load_lds(
      (const __attribute__((address_space(1))) unsigned int*)g,
      (__attribute__((address_space(3))) unsigned int*)l, 16, 0, 0);
}

// ---------- kernel: x fp32 -> bf16 ----------
__global__ void cvt_x_kernel(const float* __restrict__ x, unsigned short* __restrict__ xb, int n4) {
  int i = blockIdx.x * blockDim.x + threadIdx.x;
  int stride = gridDim.x * blockDim.x;
  for (; i < n4; i += stride) {
    float4 v = ((const float4*)x)[i];
    ushort4 o;
    o.x = f2bf(v.x); o.y = f2bf(v.y); o.z = f2bf(v.z); o.w = f2bf(v.w);
    ((ushort4*)xb)[i] = o;
  }
}

// ---------- kernel: weight transpose + cvt ----------
__global__ void cvt_wT_kernel(const float* __restrict__ W0, const float* __restrict__ W1,
                              const float* __restrict__ W2, const float* __restrict__ W3,
                              unsigned short* __restrict__ T0, unsigned short* __restrict__ T1,
                              unsigned short* __restrict__ T2, unsigned short* __restrict__ T3) {
  const float* W; unsigned short* T;
  switch (blockIdx.z) {
    case 0: W = W0; T = T0; break;
    case 1: W = W1; T = T1; break;
    case 2: W = W2; T = T2; break;
    default: W = W3; T = T3; break;
  }
  __shared__ float tile[32][33];
  int tx = threadIdx.x & 31, ty = threadIdx.x >> 5;
  int r0 = blockIdx.y * 32, c0 = blockIdx.x * 32;
#pragma unroll
  for (int i = 0; i < 4; i++) tile[ty + i * 8][tx] = W[(r0 + ty + i * 8) * 512 + c0 + tx];
  __syncthreads();
#pragma unroll
  for (int i = 0; i < 4; i++) T[(c0 + ty + i * 8) * 512 + r0 + tx] = f2bf(tile[tx][ty + i * 8]);
}

// ================= 256x256 U-GEMM, swapped-operand 4-phase schedule =================
__global__ __launch_bounds__(512, 2) void gemm256_u_kernel(
    const unsigned short* __restrict__ Q, const unsigned short* __restrict__ Kb,
    unsigned short* __restrict__ U, float* __restrict__ lpart) {
  __shared__ __align__(16) unsigned short smem[65536];
  const int tid = threadIdx.x, lane = tid & 63;
  const int w = tid >> 6;
  const int g = lane >> 4, r = lane & 15;
  const int wm2 = w & 1, wn4 = w >> 1;
  const int wgid = (blockIdx.x & 7) * 128 + (blockIdx.x >> 3);  // XCD swizzle (1024%8==0)
  const int brow = (wgid >> 5) * 256;   // q base
  const int bcol = (wgid & 31) * 256;   // k base
  const int srow = tid >> 3;            // staging row 0..63
  const int sg = tid & 7;               // staging granule

  f32x4 acc[2][2][4][2] = {};           // [kh][qh][m][n]

#define STG(b, a, h, kt)                                                                       \
  do {                                                                                         \
    const unsigned short* _src = (a) ? Kb : Q;                                                 \
    int _base = (a) ? bcol : brow;                                                             \
    int _r0 = (h) * 128 + srow;                                                                \
    int _r1 = _r0 + 64;                                                                        \
    unsigned short* _d = smem + (b) * 32768 + (a) * 16384 + (h) * 8192 + tid * 8;              \
    gll16(_src + (size_t)(_base + _r0) * 512 + (kt) * 64 + ((sg ^ (_r0 & 7)) * 8), _d);        \
    gll16(_src + (size_t)(_base + _r1) * 512 + (kt) * 64 + ((sg ^ (_r1 & 7)) * 8), _d + 4096); \
  } while (0)

  auto LDK = [&](sh8 (&kf)[2][4], int B_, int kh) {
    const unsigned short* Bs = smem + B_ * 32768 + 16384;
#pragma unroll
    for (int kk = 0; kk < 2; kk++)
#pragma unroll
      for (int m = 0; m < 4; m++) {
        int row = kh * 128 + wm2 * 64 + m * 16 + r;
        kf[kk][m] = *(const sh8*)&Bs[row * 64 + (((kk * 4 + g) ^ (r & 7)) * 8)];
      }
  };
  auto LDQ = [&](sh8 (&qf)[2][2], int B_, int qh) {
    const unsigned short* As = smem + B_ * 32768;
#pragma unroll
    for (int kk = 0; kk < 2; kk++)
#pragma unroll
      for (int n = 0; n < 2; n++) {
        int row = qh * 128 + wn4 * 32 + n * 16 + r;
        qf[kk][n] = *(const sh8*)&As[row * 64 + (((kk * 4 + g) ^ (r & 7)) * 8)];
      }
  };
  auto MM = [&](f32x4 (&c)[4][2], sh8 (&kf)[2][4], sh8 (&qf)[2][2]) {
    __builtin_amdgcn_s_setprio(1);
#pragma unroll
    for (int kk = 0; kk < 2; kk++)
#pragma unroll
      for (int m = 0; m < 4; m++)
#pragma unroll
        for (int n = 0; n < 2; n++)
          c[m][n] = mfma16(kf[kk][m], qf[kk][n], c[m][n]);
    __builtin_amdgcn_s_setprio(0);
  };
#define BAR asm volatile("s_barrier" ::: "memory")
#define VM2 asm volatile("s_waitcnt vmcnt(2)" ::: "memory")

  STG(0, 0, 0, 0); STG(0, 0, 1, 0); STG(0, 1, 0, 0); STG(0, 1, 1, 0);
  asm volatile("s_waitcnt vmcnt(0)" ::: "memory");
  BAR;

#pragma unroll
  for (int kt = 0; kt < 8; ++kt) {
    const int cur = kt & 1, nb = cur ^ 1;
    const int kn = (kt < 7) ? kt + 1 : 7;
    sh8 k0[2][4], k1[2][4], q0[2][2], q1[2][2];
    LDK(k0, cur, 0); LDQ(q0, cur, 0);
    STG(nb, 0, 0, kn);
    VM2; BAR;
    MM(acc[0][0], k0, q0);
    BAR;
    LDQ(q1, cur, 1);
    STG(nb, 0, 1, kn);
    BAR;
    MM(acc[0][1], k0, q1);
    BAR;
    LDK(k1, cur, 1);
    STG(nb, 1, 0, kn);
    BAR;
    MM(acc[1][0], k1, q0);
    BAR;
    STG(nb, 1, 1, kn);
    VM2; BAR;
    MM(acc[1][1], k1, q1);
    BAR;
  }
#undef STG

  asm volatile("s_waitcnt vmcnt(0)" ::: "memory");
  __syncthreads();

  const float K2c = 0.04419417382415922f * 1.4426950408889634f;  // 1/sqrt(512)*log2e
#pragma unroll
  for (int qh = 0; qh < 2; qh++)
#pragma unroll
    for (int n = 0; n < 2; n++) {
      int qr = qh * 128 + wn4 * 32 + n * 16 + r;
      float s = 0.f;
#pragma unroll
      for (int kh = 0; kh < 2; kh++)
#pragma unroll
        for (int m = 0; m < 4; m++) {
          f32x4 a = acc[kh][qh][m][n];
          float v0 = __builtin_amdgcn_exp2f(a[0] * K2c);
          float v1 = __builtin_amdgcn_exp2f(a[1] * K2c);
          float v2 = __builtin_amdgcn_exp2f(a[2] * K2c);
          float v3 = __builtin_amdgcn_exp2f(a[3] * K2c);
          s += (v0 + v1) + (v2 + v3);
          uint2 pk; pk.x = cvtpk(v0, v1); pk.y = cvtpk(v2, v3);
          int ke = kh * 128 + wm2 * 64 + m * 16 + g * 4;
          int el = qr * 256 + (ke ^ ((qr & 7) * 8));
          *(uint2*)&smem[el] = pk;
        }
      s += __shfl_xor(s, 16);
      s += __shfl_xor(s, 32);
      if (g == 0)
        lpart[(size_t)((bcol >> 7) + wm2) * 8192 + brow + qr] = s;
    }
  __syncthreads();
#pragma unroll
  for (int jj = 0; jj < 16; jj++) {
    int row = jj * 16 + (tid >> 5);
    int g32 = tid & 31;
    uint4 v = *(const uint4*)&smem[row * 256 + ((g32 ^ (row & 7)) * 8)];
    *(uint4*)&U[(size_t)(brow + row) * 8192 + bcol + g32 * 8] = v;
  }
}

// ================= 256x256 PV-GEMM (same skeleton), split-K=4, bf16 partials =========
// P[8192 q][512 d] partial = U[q][kz-slice] @ V[kz-slice][d]. A=U (lda 8192),
// B=VT (ldb 8192). Swapped MFMA: lane holds 4 consecutive d of one q-row.
// grid 256: bid = (qthi*2 + nt)*8 + ((qt&1)*4 + kz) -> both n-twins of a
// (qt,kz) on one XCD (U fetched once, VT slice L2-resident).
__global__ __launch_bounds__(512, 2) void gemm256_pv_kernel(
    const unsigned short* __restrict__ Uu, const unsigned short* __restrict__ VT,
    unsigned short* __restrict__ P0, unsigned short* __restrict__ P1,
    unsigned short* __restrict__ P2, unsigned short* __restrict__ P3) {
  __shared__ __align__(16) unsigned short smem[65536];
  const int tid = threadIdx.x, lane = tid & 63;
  const int w = tid >> 6;
  const int g = lane >> 4, r = lane & 15;
  const int wm2 = w & 1, wn4 = w >> 1;
  const int c = blockIdx.x & 7;
  const int hi = blockIdx.x >> 3;         // 0..31
  const int nt = hi & 1, qthi = hi >> 1;  // qthi 0..15
  const int qlo = c >> 2, kz = c & 3;
  const int qt = qthi * 2 + qlo;          // 0..31
  const int brow = qt * 256;              // q base (U rows)
  const int bcol = nt * 256;              // d base (VT rows)
  const int koff = kz * 2048;
  const int srow = tid >> 3;
  const int sg = tid & 7;
  unsigned short* P = (kz == 0) ? P0 : (kz == 1) ? P1 : (kz == 2) ? P2 : P3;

  f32x4 acc[2][2][4][2] = {};             // [dh][qh][m][n]

#define STGP(b, a, h, kt)                                                                        \
  do {                                                                                           \
    const unsigned short* _src = (a) ? VT : Uu;                                                  \
    int _base = (a) ? bcol : brow;                                                               \
    int _r0 = (h) * 128 + srow;                                                                  \
    int _r1 = _r0 + 64;                                                                          \
    unsigned short* _d = smem + (b) * 32768 + (a) * 16384 + (h) * 8192 + tid * 8;                \
    gll16(_src + (size_t)(_base + _r0) * 8192 + koff + (kt) * 64 + ((sg ^ (_r0 & 7)) * 8), _d);  \
    gll16(_src + (size_t)(_base + _r1) * 8192 + koff + (kt) * 64 + ((sg ^ (_r1 & 7)) * 8),       \
          _d + 4096);                                                                            \
  } while (0)

  auto LDV = [&](sh8 (&vf)[2][4], int B_, int dh) {
    const unsigned short* Bs = smem + B_ * 32768 + 16384;
#pragma unroll
    for (int kk = 0; kk < 2; kk++)
#pragma unroll
      for (int m = 0; m < 4; m++) {
        int row = dh * 128 + wm2 * 64 + m * 16 + r;
        vf[kk][m] = *(const sh8*)&Bs[row * 64 + (((kk * 4 + g) ^ (r & 7)) * 8)];
      }
  };
  auto LDU = [&](sh8 (&uf)[2][2], int B_, int qh) {
    const unsigned short* As = smem + B_ * 32768;
#pragma unroll
    for (int kk = 0; kk < 2; kk++)
#pragma unroll
      for (int n = 0; n < 2; n++) {
        int row = qh * 128 + wn4 * 32 + n * 16 + r;
        uf[kk][n] = *(const sh8*)&As[row * 64 + (((kk * 4 + g) ^ (r & 7)) * 8)];
      }
  };
  auto MM = [&](f32x4 (&cc)[4][2], sh8 (&vf)[2][4], sh8 (&uf)[2][2]) {
    __builtin_amdgcn_s_setprio(1);
#pragma unroll
    for (int kk = 0; kk < 2; kk++)
#pragma unroll
      for (int m = 0; m < 4; m++)
#pragma unroll
        for (int n = 0; n < 2; n++)
          cc[m][n] = mfma16(vf[kk][m], uf[kk][n], cc[m][n]);
    __builtin_amdgcn_s_setprio(0);
  };

  STGP(0, 0, 0, 0); STGP(0, 0, 1, 0); STGP(0, 1, 0, 0); STGP(0, 1, 1, 0);
  asm volatile("s_waitcnt vmcnt(0)" ::: "memory");
  BAR;

#pragma unroll 2
  for (int kt = 0; kt < 32; ++kt) {
    const int cur = kt & 1, nb = cur ^ 1;
    const int kn = (kt < 31) ? kt + 1 : 31;
    sh8 v0[2][4], v1[2][4], u0[2][2], u1[2][2];
    LDV(v0, cur, 0); LDU(u0, cur, 0);
    STGP(nb, 0, 0, kn);
    VM2; BAR;
    MM(acc[0][0], v0, u0);
    BAR;
    LDU(u1, cur, 1);
    STGP(nb, 0, 1, kn);
    BAR;
    MM(acc[0][1], v0, u1);
    BAR;
    LDV(v1, cur, 1);
    STGP(nb, 1, 0, kn);
    BAR;
    MM(acc[1][0], v1, u0);
    BAR;
    STGP(nb, 1, 1, kn);
    VM2; BAR;
    MM(acc[1][1], v1, u1);
    BAR;
  }
#undef STGP
#undef BAR
#undef VM2

  asm volatile("s_waitcnt vmcnt(0)" ::: "memory");
  __syncthreads();

  // epilogue: bf16 restage (swizzled) + coalesced 512B-row stores to partial
#pragma unroll
  for (int qh = 0; qh < 2; qh++)
#pragma unroll
    for (int n = 0; n < 2; n++) {
      int qr = qh * 128 + wn4 * 32 + n * 16 + r;
#pragma unroll
      for (int dh = 0; dh < 2; dh++)
#pragma unroll
        for (int m = 0; m < 4; m++) {
          f32x4 a = acc[dh][qh][m][n];
          uint2 pk; pk.x = cvtpk(a[0], a[1]); pk.y = cvtpk(a[2], a[3]);
          int de = dh * 128 + wm2 * 64 + m * 16 + g * 4;
          int el = qr * 256 + (de ^ ((qr & 7) * 8));
          *(uint2*)&smem[el] = pk;
        }
    }
  __syncthreads();
#pragma unroll
  for (int jj = 0; jj < 16; jj++) {
    int row = jj * 16 + (tid >> 5);
    int g32 = tid & 31;
    uint4 v = *(const uint4*)&smem[row * 256 + ((g32 ^ (row & 7)) * 8)];
    *(uint4*)&P[(size_t)(brow + row) * 512 + bcol + g32 * 8] = v;
  }
}

// ---------- 128x128 GEMM core (BK=64, dbuf + counted vmcnt) ----------
template <int MODE>
DEV void gemm_core(const unsigned short* __restrict__ A, int lda,
                   const unsigned short* __restrict__ Bt, int ldb,
                   const float* __restrict__ bias, void* __restrict__ Cv, int ldc,
                   int kSteps, int koff, int brow, int bcol,
                   unsigned short* smem) {
  const int tid = threadIdx.x, lane = tid & 63, w = tid >> 6;
  const int g = lane >> 4, r = lane & 15;
  const int wr = w >> 1, wc = w & 1;
  const int rA = w * 8 + (lane >> 3);
  const int sgl = lane & 7;
  const int scol = ((sgl ^ (lane >> 3)) * 8);
  const unsigned short* aP = A + (size_t)(brow + rA) * lda + koff + scol;
  const unsigned short* bP = Bt + (size_t)(bcol + rA) * ldb + koff + scol;
  const int lOff = rA * 64 + sgl * 8;
  f32x4 acc[4][4] = {};
  const int fr = r & 7;

  auto STAGE = [&](int buf, int ks) {
    unsigned short* lA = smem + buf * 16384 + lOff;
    unsigned short* lB = smem + buf * 16384 + 8192 + lOff;
    const size_t ko = (size_t)ks * 64;
#pragma unroll
    for (int cc = 0; cc < 4; cc++) gll16(aP + (size_t)cc * 32 * lda + ko, lA + cc * 32 * 64);
#pragma unroll
    for (int cc = 0; cc < 4; cc++) gll16(bP + (size_t)cc * 32 * ldb + ko, lB + cc * 32 * 64);
  };
  auto COMPUTE = [&](int buf) {
    const unsigned short* As = smem + buf * 16384;
    const unsigned short* Bs = As + 8192;
#pragma unroll
    for (int kk = 0; kk < 2; kk++) {
      sh8 af[4], bfr[4];
#pragma unroll
      for (int m = 0; m < 4; m++)
        af[m] = *(const sh8*)&As[(wr * 64 + m * 16 + r) * 64 + (((kk * 4 + g) ^ fr) * 8)];
#pragma unroll
      for (int n = 0; n < 4; n++)
        bfr[n] = *(const sh8*)&Bs[(wc * 64 + n * 16 + r) * 64 + (((kk * 4 + g) ^ fr) * 8)];
#pragma unroll
      for (int m = 0; m < 4; m++)
#pragma unroll
        for (int n = 0; n < 4; n++) acc[m][n] = mfma16(af[m], bfr[n], acc[m][n]);
    }
  };

  STAGE(0, 0);
  int cur = 0;
  for (int ks = 0; ks + 1 < kSteps; ks++) {
    STAGE(cur ^ 1, ks + 1);
    asm volatile("s_waitcnt vmcnt(8)" ::: "memory");
    asm volatile("s_barrier" ::: "memory");
    COMPUTE(cur);
    asm volatile("s_barrier" ::: "memory");
    cur ^= 1;
  }
  asm volatile("s_waitcnt vmcnt(0)" ::: "memory");
  asm volatile("s_barrier" ::: "memory");
  COMPUTE(cur);

  if (MODE == 0) {
#pragma unroll
    for (int n = 0; n < 4; n++) {
      int col = bcol + wc * 64 + n * 16 + r;
      float bv = bias ? bias[col] : 0.f;
#pragma unroll
      for (int m = 0; m < 4; m++) {
        int row = brow + wr * 64 + m * 16 + g * 4;
#pragma unroll
        for (int i = 0; i < 4; i++)
          ((float*)Cv)[(size_t)(row + i) * ldc + col] = acc[m][n][i] + bv;
      }
    }
  } else {
    __syncthreads();
#pragma unroll
    for (int m = 0; m < 4; m++) {
#pragma unroll
      for (int n = 0; n < 4; n++) {
        int coll = wc * 64 + n * 16 + r;
        float bv = bias ? bias[bcol + coll] : 0.f;
        int rb = (wr * 64 + m * 16 + g * 4) * 132 + coll;
        smem[rb] = f2bf(acc[m][n][0] + bv);
        smem[rb + 132] = f2bf(acc[m][n][1] + bv);
        smem[rb + 264] = f2bf(acc[m][n][2] + bv);
        smem[rb + 396] = f2bf(acc[m][n][3] + bv);
      }
    }
    __syncthreads();
    unsigned short* C = (unsigned short*)Cv;
#pragma unroll
    for (int j = 0; j < 8; j++) {
      int row = w * 32 + j * 4 + (lane >> 4);
      int colb = (lane & 15) * 8;
      uint4 v = *(const uint4*)&smem[row * 132 + colb];
      *(uint4*)&C[(size_t)(brow + row) * ldc + bcol + colb] = v;
    }
  }
}

// ---------- GEMM wrappers ----------
__global__ __launch_bounds__(256, 2) void gemm_qkv_kernel(
    const unsigned short* __restrict__ A,
    const unsigned short* __restrict__ B0, const unsigned short* __restrict__ B1,
    const unsigned short* __restrict__ B2,
    const float* __restrict__ c0, const float* __restrict__ c1, const float* __restrict__ c2,
    unsigned short* __restrict__ C0, unsigned short* __restrict__ C1,
    unsigned short* __restrict__ C2) {
  __shared__ __align__(16) unsigned short smem[32768];
  const unsigned short* Bt; const float* bias; unsigned short* C;
  switch (blockIdx.z) {
    case 0: Bt = B0; bias = c0; C = C0; break;
    case 1: Bt = B1; bias = c1; C = C1; break;
    default: Bt = B2; bias = c2; C = C2; break;
  }
  gemm_core<1>(A, 512, Bt, 512, bias, C, 512, 8, 0,
               blockIdx.x * 128, blockIdx.y * 128, smem);
}

__global__ __launch_bounds__(256, 2) void gemm_o_kernel(
    const unsigned short* __restrict__ att, const unsigned short* __restrict__ woT,
    const float* __restrict__ bo, float* __restrict__ out) {
  __shared__ __align__(16) unsigned short smem[32768];
  gemm_core<0>(att, 512, woT, 512, bo, out, 512, 8, 0,
               blockIdx.x * 128, blockIdx.y * 128, smem);
}

// ---------- kernel: v [8192][512] -> vT [512][8192] (bf16) ----------
__global__ void transpose_v_kernel(const unsigned short* __restrict__ in, unsigned short* __restrict__ out) {
  __shared__ unsigned short tile[32][33];
  int tx = threadIdx.x & 31, ty = threadIdx.x >> 5;
  int r0 = blockIdx.y * 32, c0 = blockIdx.x * 32;
#pragma unroll
  for (int i = 0; i < 4; i++) tile[ty + i * 8][tx] = in[(size_t)(r0 + ty + i * 8) * 512 + c0 + tx];
  __syncthreads();
#pragma unroll
  for (int i = 0; i < 4; i++) out[(size_t)(c0 + ty + i * 8) * 8192 + r0 + tx] = tile[tx][ty + i * 8];
}

// ---------- combine row-sum partials (64 k-chunks) -> 1/l ----------
__global__ void combine_l_kernel(const float* __restrict__ lpart, float* __restrict__ linv) {
  int row = blockIdx.x * 256 + threadIdx.x;
  float s = 0.f;
#pragma unroll 8
  for (int j = 0; j < 64; j++) s += lpart[(size_t)j * 8192 + row];
  linv[row] = 1.0f / s;
}

// ---------- add four bf16 partials * linv[row] -> bf16 ----------
__global__ void addcvt4_kernel(const unsigned short* __restrict__ p0,
                               const unsigned short* __restrict__ p1,
                               const unsigned short* __restrict__ p2,
                               const unsigned short* __restrict__ p3,
                               const float* __restrict__ linv,
                               unsigned short* __restrict__ o, int n8) {
  int i = blockIdx.x * blockDim.x + threadIdx.x;
  int stride = gridDim.x * blockDim.x;
  for (; i < n8; i += stride) {
    float inv = linv[i >> 6];
    uint4 a = ((const uint4*)p0)[i];
    uint4 b = ((const uint4*)p1)[i];
    uint4 c = ((const uint4*)p2)[i];
    uint4 d = ((const uint4*)p3)[i];
    const unsigned* ua = (const unsigned*)&a;
    const unsigned* ub = (const unsigned*)&b;
    const unsigned* uc = (const unsigned*)&c;
    const unsigned* ud = (const unsigned*)&d;
    unsigned out[4];
#pragma unroll
    for (int e = 0; e < 4; e++) {
      float lo = __uint_as_float(ua[e] << 16) + __uint_as_float(ub[e] << 16) +
                 __uint_as_float(uc[e] << 16) + __uint_as_float(ud[e] << 16);
      float hi = __uint_as_float(ua[e] & 0xffff0000u) + __uint_as_float(ub[e] & 0xffff0000u) +
                 __uint_as_float(uc[e] & 0xffff0000u) + __uint_as_float(ud[e] & 0xffff0000u);
      out[e] = cvtpk(lo * inv, hi * inv);
    }
    ((uint4*)o)[i] = *(uint4*)out;
  }
}

// ---------- launch ----------
extern "C" void kernel_launch(void* const* d_in, const int* in_sizes, int n_in,
                              void* d_out, int out_size, void* d_ws, size_t ws_size,
                              hipStream_t stream) {
  const float* x  = (const float*)d_in[0];
  const float* Wq = (const float*)d_in[1];
  const float* bq = (const float*)d_in[2];
  const float* Wk = (const float*)d_in[3];
  const float* bk = (const float*)d_in[4];
  const float* Wv = (const float*)d_in[5];
  const float* bv = (const float*)d_in[6];
  const float* Wo = (const float*)d_in[7];
  const float* bo = (const float*)d_in[8];
  char* ws = (char*)d_ws;

  unsigned short* U   = (unsigned short*)(ws + 0);          // 134.2 MB
  unsigned short* xb  = (unsigned short*)(ws + 0);          // overlay
  unsigned short* vb  = (unsigned short*)(ws + 8388608);    // overlay
  unsigned short* att = (unsigned short*)(ws + 0);          // overlay (after PV)
  unsigned short* qb  = (unsigned short*)(ws + 134217728);
  unsigned short* kb  = (unsigned short*)(ws + 142606336);
  unsigned short* vtb = (unsigned short*)(ws + 150994944);
  unsigned short* wqT = (unsigned short*)(ws + 159383552);
  unsigned short* wkT = (unsigned short*)(ws + 159907840);
  unsigned short* wvT = (unsigned short*)(ws + 160432128);
  unsigned short* woT = (unsigned short*)(ws + 160956416);
  float* lpart = (float*)(ws + 161480704);                  // 2 MB [64][8192]
  float* linv  = (float*)(ws + 165675008);                  // 32 KB
  // PV partials (bf16, 8 MB each): qb, kb dead after U-GEMM; d_out holds two.
  unsigned short* P0 = qb;
  unsigned short* P1 = kb;
  unsigned short* P2 = (unsigned short*)d_out;
  unsigned short* P3 = (unsigned short*)d_out + 4194304;

  cvt_x_kernel<<<2048, 256, 0, stream>>>(x, xb, 8192 * 512 / 4);
  cvt_wT_kernel<<<dim3(16, 16, 4), 256, 0, stream>>>(Wq, Wk, Wv, Wo, wqT, wkT, wvT, woT);
  gemm_qkv_kernel<<<dim3(64, 4, 3), 256, 0, stream>>>(
      xb, wqT, wkT, wvT, bq, bk, bv, qb, kb, vb);
  transpose_v_kernel<<<dim3(16, 256), 256, 0, stream>>>(vb, vtb);
  gemm256_u_kernel<<<1024, 512, 0, stream>>>(qb, kb, U, lpart);
  combine_l_kernel<<<32, 256, 0, stream>>>(lpart, linv);
  gemm256_pv_kernel<<<256, 512, 0, stream>>>(U, vtb, P0, P1, P2, P3);
  addcvt4_kernel<<<2048, 256, 0, stream>>>(P0, P1, P2, P3, linv, att, 8192 * 512 / 8);
  gemm_o_kernel<<<dim3(64, 4), 256, 0, stream>>>(att, woT, bo, (float*)d_out);
}

// Round 13
// 206.130 us; speedup vs baseline: 1.2626x; 1.0266x over previous
//
#include <hip/hip_runtime.h>

// ---------- common ----------
typedef short sh8 __attribute__((ext_vector_type(8)));
typedef float f32x4 __attribute__((ext_vector_type(4)));

#define DEV __device__ __forceinline__

DEV f32x4 mfma16(sh8 a, sh8 b, f32x4 c) {
  return __builtin_amdgcn_mfma_f32_16x16x32_bf16(a, b, c, 0, 0, 0);
}

DEV unsigned short f2bf(float f) {
  unsigned u = __float_as_uint(f);
  u = u + 0x7FFFu + ((u >> 16) & 1u);   // RNE
  return (unsigned short)(u >> 16);
}

DEV unsigned cvtpk(float lo, float hi) {
  unsigned r;
  asm("v_cvt_pk_bf16_f32 %0, %1, %2" : "=v"(r) : "v"(lo), "v"(hi));
  return r;
}

DEV void gll16(const void* g, void* l) {
  __builtin_amdgcn_global_load_lds(
      (const __attribute__((address_space(1))) unsigned int*)g,
      (__attribute__((address_space(3))) unsigned int*)l, 16, 0, 0);
}

// ---------- kernel: x fp32 -> bf16 ----------
__global__ void cvt_x_kernel(const float* __restrict__ x, unsigned short* __restrict__ xb, int n4) {
  int i = blockIdx.x * blockDim.x + threadIdx.x;
  int stride = gridDim.x * blockDim.x;
  for (; i < n4; i += stride) {
    float4 v = ((const float4*)x)[i];
    ushort4 o;
    o.x = f2bf(v.x); o.y = f2bf(v.y); o.z = f2bf(v.z); o.w = f2bf(v.w);
    ((ushort4*)xb)[i] = o;
  }
}

// ---------- kernel: weight transpose + cvt ----------
__global__ void cvt_wT_kernel(const float* __restrict__ W0, const float* __restrict__ W1,
                              const float* __restrict__ W2, const float* __restrict__ W3,
                              unsigned short* __restrict__ T0, unsigned short* __restrict__ T1,
                              unsigned short* __restrict__ T2, unsigned short* __restrict__ T3) {
  const float* W; unsigned short* T;
  switch (blockIdx.z) {
    case 0: W = W0; T = T0; break;
    case 1: W = W1; T = T1; break;
    case 2: W = W2; T = T2; break;
    default: W = W3; T = T3; break;
  }
  __shared__ float tile[32][33];
  int tx = threadIdx.x & 31, ty = threadIdx.x >> 5;
  int r0 = blockIdx.y * 32, c0 = blockIdx.x * 32;
#pragma unroll
  for (int i = 0; i < 4; i++) tile[ty + i * 8][tx] = W[(r0 + ty + i * 8) * 512 + c0 + tx];
  __syncthreads();
#pragma unroll
  for (int i = 0; i < 4; i++) T[(c0 + ty + i * 8) * 512 + r0 + tx] = f2bf(tile[tx][ty + i * 8]);
}

// ================= 256x256 U-GEMM, swapped-operand 4-phase schedule =================
// r11 proven wait schedule: stage order Q0,Q1,K0,K1 (all into buf nxt);
// VM2 at ph1 (covers K1(t)) and ph4 (covers Q0,Q1,K0(t+1)). Every ds_read's
// data is covered by a wait+barrier strictly before it in program order.
// XCD decode: 2D-chunked — each XCD (bid%8) owns a 16x8 tile rectangle
// (Q 4MB + K 2MB, mostly L2-resident) instead of 4 rows x 32 cols.
__global__ __launch_bounds__(512, 2) void gemm256_u_kernel(
    const unsigned short* __restrict__ Q, const unsigned short* __restrict__ Kb,
    unsigned short* __restrict__ U, float* __restrict__ lpart) {
  __shared__ __align__(16) unsigned short smem[65536];
  const int tid = threadIdx.x, lane = tid & 63;
  const int w = tid >> 6;
  const int g = lane >> 4, r = lane & 15;
  const int wm2 = w & 1, wn4 = w >> 1;
  const int xcd = blockIdx.x & 7, j = blockIdx.x >> 3;           // XCD = bid%8
  const int brow = ((xcd & 1) * 16 + (j & 15)) * 256;            // q base (16 rows/XCD)
  const int bcol = ((xcd >> 1) * 8 + (j >> 4)) * 256;            // k base (8 cols/XCD)
  const int srow = tid >> 3;            // staging row 0..63
  const int sg = tid & 7;               // staging granule

  f32x4 acc[2][2][4][2] = {};           // [kh][qh][m][n]

#define STG(b, a, h, kt)                                                                       \
  do {                                                                                         \
    const unsigned short* _src = (a) ? Kb : Q;                                                 \
    int _base = (a) ? bcol : brow;                                                             \
    int _r0 = (h) * 128 + srow;                                                                \
    int _r1 = _r0 + 64;                                                                        \
    unsigned short* _d = smem + (b) * 32768 + (a) * 16384 + (h) * 8192 + tid * 8;              \
    gll16(_src + (size_t)(_base + _r0) * 512 + (kt) * 64 + ((sg ^ (_r0 & 7)) * 8), _d);        \
    gll16(_src + (size_t)(_base + _r1) * 512 + (kt) * 64 + ((sg ^ (_r1 & 7)) * 8), _d + 4096); \
  } while (0)

  auto LDK = [&](sh8 (&kf)[2][4], int B_, int kh) {
    const unsigned short* Bs = smem + B_ * 32768 + 16384;
#pragma unroll
    for (int kk = 0; kk < 2; kk++)
#pragma unroll
      for (int m = 0; m < 4; m++) {
        int row = kh * 128 + wm2 * 64 + m * 16 + r;
        kf[kk][m] = *(const sh8*)&Bs[row * 64 + (((kk * 4 + g) ^ (r & 7)) * 8)];
      }
  };
  auto LDQ = [&](sh8 (&qf)[2][2], int B_, int qh) {
    const unsigned short* As = smem + B_ * 32768;
#pragma unroll
    for (int kk = 0; kk < 2; kk++)
#pragma unroll
      for (int n = 0; n < 2; n++) {
        int row = qh * 128 + wn4 * 32 + n * 16 + r;
        qf[kk][n] = *(const sh8*)&As[row * 64 + (((kk * 4 + g) ^ (r & 7)) * 8)];
      }
  };
  auto MM = [&](f32x4 (&c)[4][2], sh8 (&kf)[2][4], sh8 (&qf)[2][2]) {
    __builtin_amdgcn_s_setprio(1);
#pragma unroll
    for (int kk = 0; kk < 2; kk++)
#pragma unroll
      for (int m = 0; m < 4; m++)
#pragma unroll
        for (int n = 0; n < 2; n++)
          c[m][n] = mfma16(kf[kk][m], qf[kk][n], c[m][n]);
    __builtin_amdgcn_s_setprio(0);
  };
#define BAR asm volatile("s_barrier" ::: "memory")
#define VM2 asm volatile("s_waitcnt vmcnt(2)" ::: "memory")

  STG(0, 0, 0, 0); STG(0, 0, 1, 0); STG(0, 1, 0, 0); STG(0, 1, 1, 0);
  asm volatile("s_waitcnt vmcnt(0)" ::: "memory");
  BAR;

#pragma unroll
  for (int kt = 0; kt < 8; ++kt) {
    const int cur = kt & 1, nb = cur ^ 1;
    const int kn = (kt < 7) ? kt + 1 : 7;   // tail: redundant restage keeps counts uniform
    sh8 k0[2][4], k1[2][4], q0[2][2], q1[2][2];
    // ph1
    LDK(k0, cur, 0); LDQ(q0, cur, 0);
    STG(nb, 0, 0, kn);
    VM2; BAR;
    MM(acc[0][0], k0, q0);
    BAR;
    // ph2
    LDQ(q1, cur, 1);
    STG(nb, 0, 1, kn);
    BAR;
    MM(acc[0][1], k0, q1);
    BAR;
    // ph3
    LDK(k1, cur, 1);
    STG(nb, 1, 0, kn);
    BAR;
    MM(acc[1][0], k1, q0);
    BAR;
    // ph4
    STG(nb, 1, 1, kn);
    VM2; BAR;
    MM(acc[1][1], k1, q1);
    BAR;
  }
#undef STG

  asm volatile("s_waitcnt vmcnt(0)" ::: "memory");
  __syncthreads();

  const float K2c = 0.04419417382415922f * 1.4426950408889634f;  // 1/sqrt(512)*log2e
#pragma unroll
  for (int qh = 0; qh < 2; qh++)
#pragma unroll
    for (int n = 0; n < 2; n++) {
      int qr = qh * 128 + wn4 * 32 + n * 16 + r;
      float s = 0.f;
#pragma unroll
      for (int kh = 0; kh < 2; kh++)
#pragma unroll
        for (int m = 0; m < 4; m++) {
          f32x4 a = acc[kh][qh][m][n];
          float v0 = __builtin_amdgcn_exp2f(a[0] * K2c);
          float v1 = __builtin_amdgcn_exp2f(a[1] * K2c);
          float v2 = __builtin_amdgcn_exp2f(a[2] * K2c);
          float v3 = __builtin_amdgcn_exp2f(a[3] * K2c);
          s += (v0 + v1) + (v2 + v3);
          uint2 pk; pk.x = cvtpk(v0, v1); pk.y = cvtpk(v2, v3);
          int ke = kh * 128 + wm2 * 64 + m * 16 + g * 4;
          int el = qr * 256 + (ke ^ ((qr & 7) * 8));
          *(uint2*)&smem[el] = pk;
        }
      s += __shfl_xor(s, 16);
      s += __shfl_xor(s, 32);
      if (g == 0)
        lpart[(size_t)((bcol >> 7) + wm2) * 8192 + brow + qr] = s;
    }
  __syncthreads();
#pragma unroll
  for (int jj = 0; jj < 16; jj++) {
    int row = jj * 16 + (tid >> 5);
    int g32 = tid & 31;
    uint4 v = *(const uint4*)&smem[row * 256 + ((g32 ^ (row & 7)) * 8)];
    *(uint4*)&U[(size_t)(brow + row) * 8192 + bcol + g32 * 8] = v;
  }
}

// ================= 256x256 PV-GEMM (same skeleton), split-K=4, bf16 partials =========
// r11 proven wait schedule: stage order U0,U1,V0,V1; VM2 at ph1 & ph4.
__global__ __launch_bounds__(512, 2) void gemm256_pv_kernel(
    const unsigned short* __restrict__ Uu, const unsigned short* __restrict__ VT,
    unsigned short* __restrict__ P0, unsigned short* __restrict__ P1,
    unsigned short* __restrict__ P2, unsigned short* __restrict__ P3) {
  __shared__ __align__(16) unsigned short smem[65536];
  const int tid = threadIdx.x, lane = tid & 63;
  const int w = tid >> 6;
  const int g = lane >> 4, r = lane & 15;
  const int wm2 = w & 1, wn4 = w >> 1;
  const int c = blockIdx.x & 7;
  const int hi = blockIdx.x >> 3;         // 0..31
  const int nt = hi & 1, qthi = hi >> 1;  // qthi 0..15
  const int qlo = c >> 2, kz = c & 3;
  const int qt = qthi * 2 + qlo;          // 0..31
  const int brow = qt * 256;              // q base (U rows)
  const int bcol = nt * 256;              // d base (VT rows)
  const int koff = kz * 2048;
  const int srow = tid >> 3;
  const int sg = tid & 7;
  unsigned short* P = (kz == 0) ? P0 : (kz == 1) ? P1 : (kz == 2) ? P2 : P3;

  f32x4 acc[2][2][4][2] = {};             // [dh][qh][m][n]

#define STGP(b, a, h, kt)                                                                        \
  do {                                                                                           \
    const unsigned short* _src = (a) ? VT : Uu;                                                  \
    int _base = (a) ? bcol : brow;                                                               \
    int _r0 = (h) * 128 + srow;                                                                  \
    int _r1 = _r0 + 64;                                                                          \
    unsigned short* _d = smem + (b) * 32768 + (a) * 16384 + (h) * 8192 + tid * 8;                \
    gll16(_src + (size_t)(_base + _r0) * 8192 + koff + (kt) * 64 + ((sg ^ (_r0 & 7)) * 8), _d);  \
    gll16(_src + (size_t)(_base + _r1) * 8192 + koff + (kt) * 64 + ((sg ^ (_r1 & 7)) * 8),       \
          _d + 4096);                                                                            \
  } while (0)

  auto LDV = [&](sh8 (&vf)[2][4], int B_, int dh) {
    const unsigned short* Bs = smem + B_ * 32768 + 16384;
#pragma unroll
    for (int kk = 0; kk < 2; kk++)
#pragma unroll
      for (int m = 0; m < 4; m++) {
        int row = dh * 128 + wm2 * 64 + m * 16 + r;
        vf[kk][m] = *(const sh8*)&Bs[row * 64 + (((kk * 4 + g) ^ (r & 7)) * 8)];
      }
  };
  auto LDU = [&](sh8 (&uf)[2][2], int B_, int qh) {
    const unsigned short* As = smem + B_ * 32768;
#pragma unroll
    for (int kk = 0; kk < 2; kk++)
#pragma unroll
      for (int n = 0; n < 2; n++) {
        int row = qh * 128 + wn4 * 32 + n * 16 + r;
        uf[kk][n] = *(const sh8*)&As[row * 64 + (((kk * 4 + g) ^ (r & 7)) * 8)];
      }
  };
  auto MM = [&](f32x4 (&cc)[4][2], sh8 (&vf)[2][4], sh8 (&uf)[2][2]) {
    __builtin_amdgcn_s_setprio(1);
#pragma unroll
    for (int kk = 0; kk < 2; kk++)
#pragma unroll
      for (int m = 0; m < 4; m++)
#pragma unroll
        for (int n = 0; n < 2; n++)
          cc[m][n] = mfma16(vf[kk][m], uf[kk][n], cc[m][n]);
    __builtin_amdgcn_s_setprio(0);
  };

  STGP(0, 0, 0, 0); STGP(0, 0, 1, 0); STGP(0, 1, 0, 0); STGP(0, 1, 1, 0);
  asm volatile("s_waitcnt vmcnt(0)" ::: "memory");
  BAR;

#pragma unroll 2
  for (int kt = 0; kt < 32; ++kt) {
    const int cur = kt & 1, nb = cur ^ 1;
    const int kn = (kt < 31) ? kt + 1 : 31;
    sh8 v0[2][4], v1[2][4], u0[2][2], u1[2][2];
    // ph1
    LDV(v0, cur, 0); LDU(u0, cur, 0);
    STGP(nb, 0, 0, kn);
    VM2; BAR;
    MM(acc[0][0], v0, u0);
    BAR;
    // ph2
    LDU(u1, cur, 1);
    STGP(nb, 0, 1, kn);
    BAR;
    MM(acc[0][1], v0, u1);
    BAR;
    // ph3
    LDV(v1, cur, 1);
    STGP(nb, 1, 0, kn);
    BAR;
    MM(acc[1][0], v1, u0);
    BAR;
    // ph4
    STGP(nb, 1, 1, kn);
    VM2; BAR;
    MM(acc[1][1], v1, u1);
    BAR;
  }
#undef STGP
#undef BAR
#undef VM2

  asm volatile("s_waitcnt vmcnt(0)" ::: "memory");
  __syncthreads();

  // epilogue: bf16 restage (swizzled) + coalesced 512B-row stores to partial
#pragma unroll
  for (int qh = 0; qh < 2; qh++)
#pragma unroll
    for (int n = 0; n < 2; n++) {
      int qr = qh * 128 + wn4 * 32 + n * 16 + r;
#pragma unroll
      for (int dh = 0; dh < 2; dh++)
#pragma unroll
        for (int m = 0; m < 4; m++) {
          f32x4 a = acc[dh][qh][m][n];
          uint2 pk; pk.x = cvtpk(a[0], a[1]); pk.y = cvtpk(a[2], a[3]);
          int de = dh * 128 + wm2 * 64 + m * 16 + g * 4;
          int el = qr * 256 + (de ^ ((qr & 7) * 8));
          *(uint2*)&smem[el] = pk;
        }
    }
  __syncthreads();
#pragma unroll
  for (int jj = 0; jj < 16; jj++) {
    int row = jj * 16 + (tid >> 5);
    int g32 = tid & 31;
    uint4 v = *(const uint4*)&smem[row * 256 + ((g32 ^ (row & 7)) * 8)];
    *(uint4*)&P[(size_t)(brow + row) * 512 + bcol + g32 * 8] = v;
  }
}

// ---------- 128x128 GEMM core (BK=64, dbuf + counted vmcnt) ----------
template <int MODE>
DEV void gemm_core(const unsigned short* __restrict__ A, int lda,
                   const unsigned short* __restrict__ Bt, int ldb,
                   const float* __restrict__ bias, void* __restrict__ Cv, int ldc,
                   int kSteps, int koff, int brow, int bcol,
                   unsigned short* smem) {
  const int tid = threadIdx.x, lane = tid & 63, w = tid >> 6;
  const int g = lane >> 4, r = lane & 15;
  const int wr = w >> 1, wc = w & 1;
  const int rA = w * 8 + (lane >> 3);
  const int sgl = lane & 7;
  const int scol = ((sgl ^ (lane >> 3)) * 8);
  const unsigned short* aP = A + (size_t)(brow + rA) * lda + koff + scol;
  const unsigned short* bP = Bt + (size_t)(bcol + rA) * ldb + koff + scol;
  const int lOff = rA * 64 + sgl * 8;
  f32x4 acc[4][4] = {};
  const int fr = r & 7;

  auto STAGE = [&](int buf, int ks) {
    unsigned short* lA = smem + buf * 16384 + lOff;
    unsigned short* lB = smem + buf * 16384 + 8192 + lOff;
    const size_t ko = (size_t)ks * 64;
#pragma unroll
    for (int cc = 0; cc < 4; cc++) gll16(aP + (size_t)cc * 32 * lda + ko, lA + cc * 32 * 64);
#pragma unroll
    for (int cc = 0; cc < 4; cc++) gll16(bP + (size_t)cc * 32 * ldb + ko, lB + cc * 32 * 64);
  };
  auto COMPUTE = [&](int buf) {
    const unsigned short* As = smem + buf * 16384;
    const unsigned short* Bs = As + 8192;
#pragma unroll
    for (int kk = 0; kk < 2; kk++) {
      sh8 af[4], bfr[4];
#pragma unroll
      for (int m = 0; m < 4; m++)
        af[m] = *(const sh8*)&As[(wr * 64 + m * 16 + r) * 64 + (((kk * 4 + g) ^ fr) * 8)];
#pragma unroll
      for (int n = 0; n < 4; n++)
        bfr[n] = *(const sh8*)&Bs[(wc * 64 + n * 16 + r) * 64 + (((kk * 4 + g) ^ fr) * 8)];
#pragma unroll
      for (int m = 0; m < 4; m++)
#pragma unroll
        for (int n = 0; n < 4; n++) acc[m][n] = mfma16(af[m], bfr[n], acc[m][n]);
    }
  };

  STAGE(0, 0);
  int cur = 0;
  for (int ks = 0; ks + 1 < kSteps; ks++) {
    STAGE(cur ^ 1, ks + 1);
    asm volatile("s_waitcnt vmcnt(8)" ::: "memory");
    asm volatile("s_barrier" ::: "memory");
    COMPUTE(cur);
    asm volatile("s_barrier" ::: "memory");
    cur ^= 1;
  }
  asm volatile("s_waitcnt vmcnt(0)" ::: "memory");
  asm volatile("s_barrier" ::: "memory");
  COMPUTE(cur);

  if (MODE == 0) {
#pragma unroll
    for (int n = 0; n < 4; n++) {
      int col = bcol + wc * 64 + n * 16 + r;
      float bv = bias ? bias[col] : 0.f;
#pragma unroll
      for (int m = 0; m < 4; m++) {
        int row = brow + wr * 64 + m * 16 + g * 4;
#pragma unroll
        for (int i = 0; i < 4; i++)
          ((float*)Cv)[(size_t)(row + i) * ldc + col] = acc[m][n][i] + bv;
      }
    }
  } else {
    __syncthreads();
#pragma unroll
    for (int m = 0; m < 4; m++) {
#pragma unroll
      for (int n = 0; n < 4; n++) {
        int coll = wc * 64 + n * 16 + r;
        float bv = bias ? bias[bcol + coll] : 0.f;
        int rb = (wr * 64 + m * 16 + g * 4) * 132 + coll;
        smem[rb] = f2bf(acc[m][n][0] + bv);
        smem[rb + 132] = f2bf(acc[m][n][1] + bv);
        smem[rb + 264] = f2bf(acc[m][n][2] + bv);
        smem[rb + 396] = f2bf(acc[m][n][3] + bv);
      }
    }
    __syncthreads();
    unsigned short* C = (unsigned short*)Cv;
#pragma unroll
    for (int j = 0; j < 8; j++) {
      int row = w * 32 + j * 4 + (lane >> 4);
      int colb = (lane & 15) * 8;
      uint4 v = *(const uint4*)&smem[row * 132 + colb];
      *(uint4*)&C[(size_t)(brow + row) * ldc + bcol + colb] = v;
    }
  }
}

// ---------- GEMM wrappers ----------
__global__ __launch_bounds__(256, 2) void gemm_qkv_kernel(
    const unsigned short* __restrict__ A,
    const unsigned short* __restrict__ B0, const unsigned short* __restrict__ B1,
    const unsigned short* __restrict__ B2,
    const float* __restrict__ c0, const float* __restrict__ c1, const float* __restrict__ c2,
    unsigned short* __restrict__ C0, unsigned short* __restrict__ C1,
    unsigned short* __restrict__ C2) {
  __shared__ __align__(16) unsigned short smem[32768];
  const unsigned short* Bt; const float* bias; unsigned short* C;
  switch (blockIdx.z) {
    case 0: Bt = B0; bias = c0; C = C0; break;
    case 1: Bt = B1; bias = c1; C = C1; break;
    default: Bt = B2; bias = c2; C = C2; break;
  }
  gemm_core<1>(A, 512, Bt, 512, bias, C, 512, 8, 0,
               blockIdx.x * 128, blockIdx.y * 128, smem);
}

__global__ __launch_bounds__(256, 2) void gemm_o_kernel(
    const unsigned short* __restrict__ att, const unsigned short* __restrict__ woT,
    const float* __restrict__ bo, float* __restrict__ out) {
  __shared__ __align__(16) unsigned short smem[32768];
  gemm_core<0>(att, 512, woT, 512, bo, out, 512, 8, 0,
               blockIdx.x * 128, blockIdx.y * 128, smem);
}

// ---------- kernel: v [8192][512] -> vT [512][8192] (bf16) ----------
__global__ void transpose_v_kernel(const unsigned short* __restrict__ in, unsigned short* __restrict__ out) {
  __shared__ unsigned short tile[32][33];
  int tx = threadIdx.x & 31, ty = threadIdx.x >> 5;
  int r0 = blockIdx.y * 32, c0 = blockIdx.x * 32;
#pragma unroll
  for (int i = 0; i < 4; i++) tile[ty + i * 8][tx] = in[(size_t)(r0 + ty + i * 8) * 512 + c0 + tx];
  __syncthreads();
#pragma unroll
  for (int i = 0; i < 4; i++) out[(size_t)(c0 + ty + i * 8) * 8192 + r0 + tx] = tile[tx][ty + i * 8];
}

// ---------- combine row-sum partials (64 k-chunks) -> 1/l ----------
__global__ void combine_l_kernel(const float* __restrict__ lpart, float* __restrict__ linv) {
  int row = blockIdx.x * 256 + threadIdx.x;
  float s = 0.f;
#pragma unroll 8
  for (int j = 0; j < 64; j++) s += lpart[(size_t)j * 8192 + row];
  linv[row] = 1.0f / s;
}

// ---------- add four bf16 partials * linv[row] -> bf16 ----------
__global__ void addcvt4_kernel(const unsigned short* __restrict__ p0,
                               const unsigned short* __restrict__ p1,
                               const unsigned short* __restrict__ p2,
                               const unsigned short* __restrict__ p3,
                               const float* __restrict__ linv,
                               unsigned short* __restrict__ o, int n8) {
  int i = blockIdx.x * blockDim.x + threadIdx.x;
  int stride = gridDim.x * blockDim.x;
  for (; i < n8; i += stride) {
    float inv = linv[i >> 6];
    uint4 a = ((const uint4*)p0)[i];
    uint4 b = ((const uint4*)p1)[i];
    uint4 c = ((const uint4*)p2)[i];
    uint4 d = ((const uint4*)p3)[i];
    const unsigned* ua = (const unsigned*)&a;
    const unsigned* ub = (const unsigned*)&b;
    const unsigned* uc = (const unsigned*)&c;
    const unsigned* ud = (const unsigned*)&d;
    unsigned out[4];
#pragma unroll
    for (int e = 0; e < 4; e++) {
      float lo = __uint_as_float(ua[e] << 16) + __uint_as_float(ub[e] << 16) +
                 __uint_as_float(uc[e] << 16) + __uint_as_float(ud[e] << 16);
      float hi = __uint_as_float(ua[e] & 0xffff0000u) + __uint_as_float(ub[e] & 0xffff0000u) +
                 __uint_as_float(uc[e] & 0xffff0000u) + __uint_as_float(ud[e] & 0xffff0000u);
      out[e] = cvtpk(lo * inv, hi * inv);
    }
    ((uint4*)o)[i] = *(uint4*)out;
  }
}

// ---------- launch ----------
extern "C" void kernel_launch(void* const* d_in, const int* in_sizes, int n_in,
                              void* d_out, int out_size, void* d_ws, size_t ws_size,
                              hipStream_t stream) {
  const float* x  = (const float*)d_in[0];
  const float* Wq = (const float*)d_in[1];
  const float* bq = (const float*)d_in[2];
  const float* Wk = (const float*)d_in[3];
  const float* bk = (const float*)d_in[4];
  const float* Wv = (const float*)d_in[5];
  const float* bv = (const float*)d_in[6];
  const float* Wo = (const float*)d_in[7];
  const float* bo = (const float*)d_in[8];
  char* ws = (char*)d_ws;

  unsigned short* U   = (unsigned short*)(ws + 0);          // 134.2 MB
  unsigned short* xb  = (unsigned short*)(ws + 0);          // overlay
  unsigned short* vb  = (unsigned short*)(ws + 8388608);    // overlay
  unsigned short* att = (unsigned short*)(ws + 0);          // overlay (after PV)
  unsigned short* qb  = (unsigned short*)(ws + 134217728);
  unsigned short* kb  = (unsigned short*)(ws + 142606336);
  unsigned short* vtb = (unsigned short*)(ws + 150994944);
  unsigned short* wqT = (unsigned short*)(ws + 159383552);
  unsigned short* wkT = (unsigned short*)(ws + 159907840);
  unsigned short* wvT = (unsigned short*)(ws + 160432128);
  unsigned short* woT = (unsigned short*)(ws + 160956416);
  float* lpart = (float*)(ws + 161480704);                  // 2 MB [64][8192]
  float* linv  = (float*)(ws + 165675008);                  // 32 KB
  unsigned short* P0 = qb;
  unsigned short* P1 = kb;
  unsigned short* P2 = (unsigned short*)d_out;
  unsigned short* P3 = (unsigned short*)d_out + 4194304;

  cvt_x_kernel<<<2048, 256, 0, stream>>>(x, xb, 8192 * 512 / 4);
  cvt_wT_kernel<<<dim3(16, 16, 4), 256, 0, stream>>>(Wq, Wk, Wv, Wo, wqT, wkT, wvT, woT);
  gemm_qkv_kernel<<<dim3(64, 4, 3), 256, 0, stream>>>(
      xb, wqT, wkT, wvT, bq, bk, bv, qb, kb, vb);
  transpose_v_kernel<<<dim3(16, 256), 256, 0, stream>>>(vb, vtb);
  gemm256_u_kernel<<<1024, 512, 0, stream>>>(qb, kb, U, lpart);
  combine_l_kernel<<<32, 256, 0, stream>>>(lpart, linv);
  gemm256_pv_kernel<<<256, 512, 0, stream>>>(U, vtb, P0, P1, P2, P3);
  addcvt4_kernel<<<2048, 256, 0, stream>>>(P0, P1, P2, P3, linv, att, 8192 * 512 / 8);
  gemm_o_kernel<<<dim3(64, 4), 256, 0, stream>>>(att, woT, bo, (float*)d_out);
}

// Round 14
// 204.787 us; speedup vs baseline: 1.2708x; 1.0066x over previous
//
#include <hip/hip_runtime.h>

// ---------- common ----------
typedef short sh8 __attribute__((ext_vector_type(8)));
typedef float f32x4 __attribute__((ext_vector_type(4)));

#define DEV __device__ __forceinline__

DEV f32x4 mfma16(sh8 a, sh8 b, f32x4 c) {
  return __builtin_amdgcn_mfma_f32_16x16x32_bf16(a, b, c, 0, 0, 0);
}

DEV unsigned short f2bf(float f) {
  unsigned u = __float_as_uint(f);
  u = u + 0x7FFFu + ((u >> 16) & 1u);   // RNE
  return (unsigned short)(u >> 16);
}

DEV unsigned cvtpk(float lo, float hi) {
  unsigned r;
  asm("v_cvt_pk_bf16_f32 %0, %1, %2" : "=v"(r) : "v"(lo), "v"(hi));
  return r;
}

DEV void gll16(const void* g, void* l) {
  __builtin_amdgcn_global_load_lds(
      (const __attribute__((address_space(1))) unsigned int*)g,
      (__attribute__((address_space(3))) unsigned int*)l, 16, 0, 0);
}

// ---------- kernel: x fp32 -> bf16 ----------
__global__ void cvt_x_kernel(const float* __restrict__ x, unsigned short* __restrict__ xb, int n4) {
  int i = blockIdx.x * blockDim.x + threadIdx.x;
  int stride = gridDim.x * blockDim.x;
  for (; i < n4; i += stride) {
    float4 v = ((const float4*)x)[i];
    ushort4 o;
    o.x = f2bf(v.x); o.y = f2bf(v.y); o.z = f2bf(v.z); o.w = f2bf(v.w);
    ((ushort4*)xb)[i] = o;
  }
}

// ---------- kernel: weight transpose + cvt ----------
__global__ void cvt_wT_kernel(const float* __restrict__ W0, const float* __restrict__ W1,
                              const float* __restrict__ W2, const float* __restrict__ W3,
                              unsigned short* __restrict__ T0, unsigned short* __restrict__ T1,
                              unsigned short* __restrict__ T2, unsigned short* __restrict__ T3) {
  const float* W; unsigned short* T;
  switch (blockIdx.z) {
    case 0: W = W0; T = T0; break;
    case 1: W = W1; T = T1; break;
    case 2: W = W2; T = T2; break;
    default: W = W3; T = T3; break;
  }
  __shared__ float tile[32][33];
  int tx = threadIdx.x & 31, ty = threadIdx.x >> 5;
  int r0 = blockIdx.y * 32, c0 = blockIdx.x * 32;
#pragma unroll
  for (int i = 0; i < 4; i++) tile[ty + i * 8][tx] = W[(r0 + ty + i * 8) * 512 + c0 + tx];
  __syncthreads();
#pragma unroll
  for (int i = 0; i < 4; i++) T[(c0 + ty + i * 8) * 512 + r0 + tx] = f2bf(tile[tx][ty + i * 8]);
}

// ================= 256x256 U-GEMM, swapped-operand 4-phase schedule =================
// r13 wait coverage (VM2 at ph1 covers K1(t); VM2 at ph4 covers Q0,Q1,K0(t+1));
// ONE barrier per phase (before MM). Safety: a wave issuing ph1(t)'s STG into
// nb=cur(t-1) has passed ph4(t-1)'s barrier -> all waves' last reads of that
// buffer (ph3(t-1), consumed by ph3's MM before its barrier+1 phase) are done.
// XCD decode: 2D-chunked (each XCD owns 16x8 tile rectangle).
__global__ __launch_bounds__(512, 2) void gemm256_u_kernel(
    const unsigned short* __restrict__ Q, const unsigned short* __restrict__ Kb,
    unsigned short* __restrict__ U, float* __restrict__ lpart) {
  __shared__ __align__(16) unsigned short smem[65536];
  const int tid = threadIdx.x, lane = tid & 63;
  const int w = tid >> 6;
  const int g = lane >> 4, r = lane & 15;
  const int wm2 = w & 1, wn4 = w >> 1;
  const int xcd = blockIdx.x & 7, j = blockIdx.x >> 3;           // XCD = bid%8
  const int brow = ((xcd & 1) * 16 + (j & 15)) * 256;            // q base (16 rows/XCD)
  const int bcol = ((xcd >> 1) * 8 + (j >> 4)) * 256;            // k base (8 cols/XCD)
  const int srow = tid >> 3;            // staging row 0..63
  const int sg = tid & 7;               // staging granule

  f32x4 acc[2][2][4][2] = {};           // [kh][qh][m][n]

#define STG(b, a, h, kt)                                                                       \
  do {                                                                                         \
    const unsigned short* _src = (a) ? Kb : Q;                                                 \
    int _base = (a) ? bcol : brow;                                                             \
    int _r0 = (h) * 128 + srow;                                                                \
    int _r1 = _r0 + 64;                                                                        \
    unsigned short* _d = smem + (b) * 32768 + (a) * 16384 + (h) * 8192 + tid * 8;              \
    gll16(_src + (size_t)(_base + _r0) * 512 + (kt) * 64 + ((sg ^ (_r0 & 7)) * 8), _d);        \
    gll16(_src + (size_t)(_base + _r1) * 512 + (kt) * 64 + ((sg ^ (_r1 & 7)) * 8), _d + 4096); \
  } while (0)

  auto LDK = [&](sh8 (&kf)[2][4], int B_, int kh) {
    const unsigned short* Bs = smem + B_ * 32768 + 16384;
#pragma unroll
    for (int kk = 0; kk < 2; kk++)
#pragma unroll
      for (int m = 0; m < 4; m++) {
        int row = kh * 128 + wm2 * 64 + m * 16 + r;
        kf[kk][m] = *(const sh8*)&Bs[row * 64 + (((kk * 4 + g) ^ (r & 7)) * 8)];
      }
  };
  auto LDQ = [&](sh8 (&qf)[2][2], int B_, int qh) {
    const unsigned short* As = smem + B_ * 32768;
#pragma unroll
    for (int kk = 0; kk < 2; kk++)
#pragma unroll
      for (int n = 0; n < 2; n++) {
        int row = qh * 128 + wn4 * 32 + n * 16 + r;
        qf[kk][n] = *(const sh8*)&As[row * 64 + (((kk * 4 + g) ^ (r & 7)) * 8)];
      }
  };
  auto MM = [&](f32x4 (&c)[4][2], sh8 (&kf)[2][4], sh8 (&qf)[2][2]) {
    __builtin_amdgcn_s_setprio(1);
#pragma unroll
    for (int kk = 0; kk < 2; kk++)
#pragma unroll
      for (int m = 0; m < 4; m++)
#pragma unroll
        for (int n = 0; n < 2; n++)
          c[m][n] = mfma16(kf[kk][m], qf[kk][n], c[m][n]);
    __builtin_amdgcn_s_setprio(0);
  };
#define BAR asm volatile("s_barrier" ::: "memory")
#define VM2 asm volatile("s_waitcnt vmcnt(2)" ::: "memory")

  STG(0, 0, 0, 0); STG(0, 0, 1, 0); STG(0, 1, 0, 0); STG(0, 1, 1, 0);
  asm volatile("s_waitcnt vmcnt(0)" ::: "memory");
  BAR;

#pragma unroll
  for (int kt = 0; kt < 8; ++kt) {
    const int cur = kt & 1, nb = cur ^ 1;
    const int kn = (kt < 7) ? kt + 1 : 7;   // tail: redundant restage keeps counts uniform
    sh8 k0[2][4], k1[2][4], q0[2][2], q1[2][2];
    // ph1
    LDK(k0, cur, 0); LDQ(q0, cur, 0);
    STG(nb, 0, 0, kn);
    VM2; BAR;
    MM(acc[0][0], k0, q0);
    // ph2
    LDQ(q1, cur, 1);
    STG(nb, 0, 1, kn);
    BAR;
    MM(acc[0][1], k0, q1);
    // ph3
    LDK(k1, cur, 1);
    STG(nb, 1, 0, kn);
    BAR;
    MM(acc[1][0], k1, q0);
    // ph4
    STG(nb, 1, 1, kn);
    VM2; BAR;
    MM(acc[1][1], k1, q1);
  }
#undef STG

  asm volatile("s_waitcnt vmcnt(0)" ::: "memory");
  __syncthreads();

  const float K2c = 0.04419417382415922f * 1.4426950408889634f;  // 1/sqrt(512)*log2e
#pragma unroll
  for (int qh = 0; qh < 2; qh++)
#pragma unroll
    for (int n = 0; n < 2; n++) {
      int qr = qh * 128 + wn4 * 32 + n * 16 + r;
      float s = 0.f;
#pragma unroll
      for (int kh = 0; kh < 2; kh++)
#pragma unroll
        for (int m = 0; m < 4; m++) {
          f32x4 a = acc[kh][qh][m][n];
          float v0 = __builtin_amdgcn_exp2f(a[0] * K2c);
          float v1 = __builtin_amdgcn_exp2f(a[1] * K2c);
          float v2 = __builtin_amdgcn_exp2f(a[2] * K2c);
          float v3 = __builtin_amdgcn_exp2f(a[3] * K2c);
          s += (v0 + v1) + (v2 + v3);
          uint2 pk; pk.x = cvtpk(v0, v1); pk.y = cvtpk(v2, v3);
          int ke = kh * 128 + wm2 * 64 + m * 16 + g * 4;
          int el = qr * 256 + (ke ^ ((qr & 7) * 8));
          *(uint2*)&smem[el] = pk;
        }
      s += __shfl_xor(s, 16);
      s += __shfl_xor(s, 32);
      if (g == 0)
        lpart[(size_t)((bcol >> 7) + wm2) * 8192 + brow + qr] = s;
    }
  __syncthreads();
#pragma unroll
  for (int jj = 0; jj < 16; jj++) {
    int row = jj * 16 + (tid >> 5);
    int g32 = tid & 31;
    uint4 v = *(const uint4*)&smem[row * 256 + ((g32 ^ (row & 7)) * 8)];
    *(uint4*)&U[(size_t)(brow + row) * 8192 + bcol + g32 * 8] = v;
  }
}

// ================= 256x256 PV-GEMM (same skeleton), split-K=4, bf16 partials =========
// Same one-barrier-per-phase schedule; stage order U0,U1,V0,V1; VM2 ph1 & ph4.
__global__ __launch_bounds__(512, 2) void gemm256_pv_kernel(
    const unsigned short* __restrict__ Uu, const unsigned short* __restrict__ VT,
    unsigned short* __restrict__ P0, unsigned short* __restrict__ P1,
    unsigned short* __restrict__ P2, unsigned short* __restrict__ P3) {
  __shared__ __align__(16) unsigned short smem[65536];
  const int tid = threadIdx.x, lane = tid & 63;
  const int w = tid >> 6;
  const int g = lane >> 4, r = lane & 15;
  const int wm2 = w & 1, wn4 = w >> 1;
  const int c = blockIdx.x & 7;
  const int hi = blockIdx.x >> 3;         // 0..31
  const int nt = hi & 1, qthi = hi >> 1;  // qthi 0..15
  const int qlo = c >> 2, kz = c & 3;
  const int qt = qthi * 2 + qlo;          // 0..31
  const int brow = qt * 256;              // q base (U rows)
  const int bcol = nt * 256;              // d base (VT rows)
  const int koff = kz * 2048;
  const int srow = tid >> 3;
  const int sg = tid & 7;
  unsigned short* P = (kz == 0) ? P0 : (kz == 1) ? P1 : (kz == 2) ? P2 : P3;

  f32x4 acc[2][2][4][2] = {};             // [dh][qh][m][n]

#define STGP(b, a, h, kt)                                                                        \
  do {                                                                                           \
    const unsigned short* _src = (a) ? VT : Uu;                                                  \
    int _base = (a) ? bcol : brow;                                                               \
    int _r0 = (h) * 128 + srow;                                                                  \
    int _r1 = _r0 + 64;                                                                          \
    unsigned short* _d = smem + (b) * 32768 + (a) * 16384 + (h) * 8192 + tid * 8;                \
    gll16(_src + (size_t)(_base + _r0) * 8192 + koff + (kt) * 64 + ((sg ^ (_r0 & 7)) * 8), _d);  \
    gll16(_src + (size_t)(_base + _r1) * 8192 + koff + (kt) * 64 + ((sg ^ (_r1 & 7)) * 8),       \
          _d + 4096);                                                                            \
  } while (0)

  auto LDV = [&](sh8 (&vf)[2][4], int B_, int dh) {
    const unsigned short* Bs = smem + B_ * 32768 + 16384;
#pragma unroll
    for (int kk = 0; kk < 2; kk++)
#pragma unroll
      for (int m = 0; m < 4; m++) {
        int row = dh * 128 + wm2 * 64 + m * 16 + r;
        vf[kk][m] = *(const sh8*)&Bs[row * 64 + (((kk * 4 + g) ^ (r & 7)) * 8)];
      }
  };
  auto LDU = [&](sh8 (&uf)[2][2], int B_, int qh) {
    const unsigned short* As = smem + B_ * 32768;
#pragma unroll
    for (int kk = 0; kk < 2; kk++)
#pragma unroll
      for (int n = 0; n < 2; n++) {
        int row = qh * 128 + wn4 * 32 + n * 16 + r;
        uf[kk][n] = *(const sh8*)&As[row * 64 + (((kk * 4 + g) ^ (r & 7)) * 8)];
      }
  };
  auto MM = [&](f32x4 (&cc)[4][2], sh8 (&vf)[2][4], sh8 (&uf)[2][2]) {
    __builtin_amdgcn_s_setprio(1);
#pragma unroll
    for (int kk = 0; kk < 2; kk++)
#pragma unroll
      for (int m = 0; m < 4; m++)
#pragma unroll
        for (int n = 0; n < 2; n++)
          cc[m][n] = mfma16(vf[kk][m], uf[kk][n], cc[m][n]);
    __builtin_amdgcn_s_setprio(0);
  };

  STGP(0, 0, 0, 0); STGP(0, 0, 1, 0); STGP(0, 1, 0, 0); STGP(0, 1, 1, 0);
  asm volatile("s_waitcnt vmcnt(0)" ::: "memory");
  BAR;

#pragma unroll 2
  for (int kt = 0; kt < 32; ++kt) {
    const int cur = kt & 1, nb = cur ^ 1;
    const int kn = (kt < 31) ? kt + 1 : 31;
    sh8 v0[2][4], v1[2][4], u0[2][2], u1[2][2];
    // ph1
    LDV(v0, cur, 0); LDU(u0, cur, 0);
    STGP(nb, 0, 0, kn);
    VM2; BAR;
    MM(acc[0][0], v0, u0);
    // ph2
    LDU(u1, cur, 1);
    STGP(nb, 0, 1, kn);
    BAR;
    MM(acc[0][1], v0, u1);
    // ph3
    LDV(v1, cur, 1);
    STGP(nb, 1, 0, kn);
    BAR;
    MM(acc[1][0], v1, u0);
    // ph4
    STGP(nb, 1, 1, kn);
    VM2; BAR;
    MM(acc[1][1], v1, u1);
  }
#undef STGP
#undef BAR
#undef VM2

  asm volatile("s_waitcnt vmcnt(0)" ::: "memory");
  __syncthreads();

  // epilogue: bf16 restage (swizzled) + coalesced 512B-row stores to partial
#pragma unroll
  for (int qh = 0; qh < 2; qh++)
#pragma unroll
    for (int n = 0; n < 2; n++) {
      int qr = qh * 128 + wn4 * 32 + n * 16 + r;
#pragma unroll
      for (int dh = 0; dh < 2; dh++)
#pragma unroll
        for (int m = 0; m < 4; m++) {
          f32x4 a = acc[dh][qh][m][n];
          uint2 pk; pk.x = cvtpk(a[0], a[1]); pk.y = cvtpk(a[2], a[3]);
          int de = dh * 128 + wm2 * 64 + m * 16 + g * 4;
          int el = qr * 256 + (de ^ ((qr & 7) * 8));
          *(uint2*)&smem[el] = pk;
        }
    }
  __syncthreads();
#pragma unroll
  for (int jj = 0; jj < 16; jj++) {
    int row = jj * 16 + (tid >> 5);
    int g32 = tid & 31;
    uint4 v = *(const uint4*)&smem[row * 256 + ((g32 ^ (row & 7)) * 8)];
    *(uint4*)&P[(size_t)(brow + row) * 512 + bcol + g32 * 8] = v;
  }
}

// ---------- 128x128 GEMM core (BK=64, dbuf + counted vmcnt) ----------
template <int MODE>
DEV void gemm_core(const unsigned short* __restrict__ A, int lda,
                   const unsigned short* __restrict__ Bt, int ldb,
                   const float* __restrict__ bias, void* __restrict__ Cv, int ldc,
                   int kSteps, int koff, int brow, int bcol,
                   unsigned short* smem) {
  const int tid = threadIdx.x, lane = tid & 63, w = tid >> 6;
  const int g = lane >> 4, r = lane & 15;
  const int wr = w >> 1, wc = w & 1;
  const int rA = w * 8 + (lane >> 3);
  const int sgl = lane & 7;
  const int scol = ((sgl ^ (lane >> 3)) * 8);
  const unsigned short* aP = A + (size_t)(brow + rA) * lda + koff + scol;
  const unsigned short* bP = Bt + (size_t)(bcol + rA) * ldb + koff + scol;
  const int lOff = rA * 64 + sgl * 8;
  f32x4 acc[4][4] = {};
  const int fr = r & 7;

  auto STAGE = [&](int buf, int ks) {
    unsigned short* lA = smem + buf * 16384 + lOff;
    unsigned short* lB = smem + buf * 16384 + 8192 + lOff;
    const size_t ko = (size_t)ks * 64;
#pragma unroll
    for (int cc = 0; cc < 4; cc++) gll16(aP + (size_t)cc * 32 * lda + ko, lA + cc * 32 * 64);
#pragma unroll
    for (int cc = 0; cc < 4; cc++) gll16(bP + (size_t)cc * 32 * ldb + ko, lB + cc * 32 * 64);
  };
  auto COMPUTE = [&](int buf) {
    const unsigned short* As = smem + buf * 16384;
    const unsigned short* Bs = As + 8192;
#pragma unroll
    for (int kk = 0; kk < 2; kk++) {
      sh8 af[4], bfr[4];
#pragma unroll
      for (int m = 0; m < 4; m++)
        af[m] = *(const sh8*)&As[(wr * 64 + m * 16 + r) * 64 + (((kk * 4 + g) ^ fr) * 8)];
#pragma unroll
      for (int n = 0; n < 4; n++)
        bfr[n] = *(const sh8*)&Bs[(wc * 64 + n * 16 + r) * 64 + (((kk * 4 + g) ^ fr) * 8)];
#pragma unroll
      for (int m = 0; m < 4; m++)
#pragma unroll
        for (int n = 0; n < 4; n++) acc[m][n] = mfma16(af[m], bfr[n], acc[m][n]);
    }
  };

  STAGE(0, 0);
  int cur = 0;
  for (int ks = 0; ks + 1 < kSteps; ks++) {
    STAGE(cur ^ 1, ks + 1);
    asm volatile("s_waitcnt vmcnt(8)" ::: "memory");
    asm volatile("s_barrier" ::: "memory");
    COMPUTE(cur);
    asm volatile("s_barrier" ::: "memory");
    cur ^= 1;
  }
  asm volatile("s_waitcnt vmcnt(0)" ::: "memory");
  asm volatile("s_barrier" ::: "memory");
  COMPUTE(cur);

  if (MODE == 0) {
#pragma unroll
    for (int n = 0; n < 4; n++) {
      int col = bcol + wc * 64 + n * 16 + r;
      float bv = bias ? bias[col] : 0.f;
#pragma unroll
      for (int m = 0; m < 4; m++) {
        int row = brow + wr * 64 + m * 16 + g * 4;
#pragma unroll
        for (int i = 0; i < 4; i++)
          ((float*)Cv)[(size_t)(row + i) * ldc + col] = acc[m][n][i] + bv;
      }
    }
  } else {
    __syncthreads();
#pragma unroll
    for (int m = 0; m < 4; m++) {
#pragma unroll
      for (int n = 0; n < 4; n++) {
        int coll = wc * 64 + n * 16 + r;
        float bv = bias ? bias[bcol + coll] : 0.f;
        int rb = (wr * 64 + m * 16 + g * 4) * 132 + coll;
        smem[rb] = f2bf(acc[m][n][0] + bv);
        smem[rb + 132] = f2bf(acc[m][n][1] + bv);
        smem[rb + 264] = f2bf(acc[m][n][2] + bv);
        smem[rb + 396] = f2bf(acc[m][n][3] + bv);
      }
    }
    __syncthreads();
    unsigned short* C = (unsigned short*)Cv;
#pragma unroll
    for (int j = 0; j < 8; j++) {
      int row = w * 32 + j * 4 + (lane >> 4);
      int colb = (lane & 15) * 8;
      uint4 v = *(const uint4*)&smem[row * 132 + colb];
      *(uint4*)&C[(size_t)(brow + row) * ldc + bcol + colb] = v;
    }
  }
}

// ---------- GEMM wrappers ----------
__global__ __launch_bounds__(256, 2) void gemm_qkv_kernel(
    const unsigned short* __restrict__ A,
    const unsigned short* __restrict__ B0, const unsigned short* __restrict__ B1,
    const unsigned short* __restrict__ B2,
    const float* __restrict__ c0, const float* __restrict__ c1, const float* __restrict__ c2,
    unsigned short* __restrict__ C0, unsigned short* __restrict__ C1,
    unsigned short* __restrict__ C2) {
  __shared__ __align__(16) unsigned short smem[32768];
  const unsigned short* Bt; const float* bias; unsigned short* C;
  switch (blockIdx.z) {
    case 0: Bt = B0; bias = c0; C = C0; break;
    case 1: Bt = B1; bias = c1; C = C1; break;
    default: Bt = B2; bias = c2; C = C2; break;
  }
  gemm_core<1>(A, 512, Bt, 512, bias, C, 512, 8, 0,
               blockIdx.x * 128, blockIdx.y * 128, smem);
}

__global__ __launch_bounds__(256, 2) void gemm_o_kernel(
    const unsigned short* __restrict__ att, const unsigned short* __restrict__ woT,
    const float* __restrict__ bo, float* __restrict__ out) {
  __shared__ __align__(16) unsigned short smem[32768];
  gemm_core<0>(att, 512, woT, 512, bo, out, 512, 8, 0,
               blockIdx.x * 128, blockIdx.y * 128, smem);
}

// ---------- kernel: v [8192][512] -> vT [512][8192] (bf16) ----------
__global__ void transpose_v_kernel(const unsigned short* __restrict__ in, unsigned short* __restrict__ out) {
  __shared__ unsigned short tile[32][33];
  int tx = threadIdx.x & 31, ty = threadIdx.x >> 5;
  int r0 = blockIdx.y * 32, c0 = blockIdx.x * 32;
#pragma unroll
  for (int i = 0; i < 4; i++) tile[ty + i * 8][tx] = in[(size_t)(r0 + ty + i * 8) * 512 + c0 + tx];
  __syncthreads();
#pragma unroll
  for (int i = 0; i < 4; i++) out[(size_t)(c0 + ty + i * 8) * 8192 + r0 + tx] = tile[tx][ty + i * 8];
}

// ---------- combine row-sum partials (64 k-chunks) -> 1/l ----------
__global__ void combine_l_kernel(const float* __restrict__ lpart, float* __restrict__ linv) {
  int row = blockIdx.x * 256 + threadIdx.x;
  float s = 0.f;
#pragma unroll 8
  for (int j = 0; j < 64; j++) s += lpart[(size_t)j * 8192 + row];
  linv[row] = 1.0f / s;
}

// ---------- add four bf16 partials * linv[row] -> bf16 ----------
__global__ void addcvt4_kernel(const unsigned short* __restrict__ p0,
                               const unsigned short* __restrict__ p1,
                               const unsigned short* __restrict__ p2,
                               const unsigned short* __restrict__ p3,
                               const float* __restrict__ linv,
                               unsigned short* __restrict__ o, int n8) {
  int i = blockIdx.x * blockDim.x + threadIdx.x;
  int stride = gridDim.x * blockDim.x;
  for (; i < n8; i += stride) {
    float inv = linv[i >> 6];
    uint4 a = ((const uint4*)p0)[i];
    uint4 b = ((const uint4*)p1)[i];
    uint4 c = ((const uint4*)p2)[i];
    uint4 d = ((const uint4*)p3)[i];
    const unsigned* ua = (const unsigned*)&a;
    const unsigned* ub = (const unsigned*)&b;
    const unsigned* uc = (const unsigned*)&c;
    const unsigned* ud = (const unsigned*)&d;
    unsigned out[4];
#pragma unroll
    for (int e = 0; e < 4; e++) {
      float lo = __uint_as_float(ua[e] << 16) + __uint_as_float(ub[e] << 16) +
                 __uint_as_float(uc[e] << 16) + __uint_as_float(ud[e] << 16);
      float hi = __uint_as_float(ua[e] & 0xffff0000u) + __uint_as_float(ub[e] & 0xffff0000u) +
                 __uint_as_float(uc[e] & 0xffff0000u) + __uint_as_float(ud[e] & 0xffff0000u);
      out[e] = cvtpk(lo * inv, hi * inv);
    }
    ((uint4*)o)[i] = *(uint4*)out;
  }
}

// ---------- launch ----------
extern "C" void kernel_launch(void* const* d_in, const int* in_sizes, int n_in,
                              void* d_out, int out_size, void* d_ws, size_t ws_size,
                              hipStream_t stream) {
  const float* x  = (const float*)d_in[0];
  const float* Wq = (const float*)d_in[1];
  const float* bq = (const float*)d_in[2];
  const float* Wk = (const float*)d_in[3];
  const float* bk = (const float*)d_in[4];
  const float* Wv = (const float*)d_in[5];
  const float* bv = (const float*)d_in[6];
  const float* Wo = (const float*)d_in[7];
  const float* bo = (const float*)d_in[8];
  char* ws = (char*)d_ws;

  unsigned short* U   = (unsigned short*)(ws + 0);          // 134.2 MB
  unsigned short* xb  = (unsigned short*)(ws + 0);          // overlay
  unsigned short* vb  = (unsigned short*)(ws + 8388608);    // overlay
  unsigned short* att = (unsigned short*)(ws + 0);          // overlay (after PV)
  unsigned short* qb  = (unsigned short*)(ws + 134217728);
  unsigned short* kb  = (unsigned short*)(ws + 142606336);
  unsigned short* vtb = (unsigned short*)(ws + 150994944);
  unsigned short* wqT = (unsigned short*)(ws + 159383552);
  unsigned short* wkT = (unsigned short*)(ws + 159907840);
  unsigned short* wvT = (unsigned short*)(ws + 160432128);
  unsigned short* woT = (unsigned short*)(ws + 160956416);
  float* lpart = (float*)(ws + 161480704);                  // 2 MB [64][8192]
  float* linv  = (float*)(ws + 165675008);                  // 32 KB
  unsigned short* P0 = qb;
  unsigned short* P1 = kb;
  unsigned short* P2 = (unsigned short*)d_out;
  unsigned short* P3 = (unsigned short*)d_out + 4194304;

  cvt_x_kernel<<<2048, 256, 0, stream>>>(x, xb, 8192 * 512 / 4);
  cvt_wT_kernel<<<dim3(16, 16, 4), 256, 0, stream>>>(Wq, Wk, Wv, Wo, wqT, wkT, wvT, woT);
  gemm_qkv_kernel<<<dim3(64, 4, 3), 256, 0, stream>>>(
      xb, wqT, wkT, wvT, bq, bk, bv, qb, kb, vb);
  transpose_v_kernel<<<dim3(16, 256), 256, 0, stream>>>(vb, vtb);
  gemm256_u_kernel<<<1024, 512, 0, stream>>>(qb, kb, U, lpart);
  combine_l_kernel<<<32, 256, 0, stream>>>(lpart, linv);
  gemm256_pv_kernel<<<256, 512, 0, stream>>>(U, vtb, P0, P1, P2, P3);
  addcvt4_kernel<<<2048, 256, 0, stream>>>(P0, P1, P2, P3, linv, att, 8192 * 512 / 8);
  gemm_o_kernel<<<dim3(64, 4), 256, 0, stream>>>(att, woT, bo, (float*)d_out);
}